// Round 11
// baseline (170.509 us; speedup 1.0000x reference)
//
#include <hip/hip_runtime.h>

// Problem constants (fixed by setup_inputs: T=8, N=2048, D=256)
#define T_ALL 8
#define T1    7
#define NPTS  2048
#define DD    256
#define NPB   16                     // 128-col blocks per frame
#define MARGIN_THR 2.0e-4f           // 2x the 9.6e-5 rigorous (C-S) margin bound
#define RC_COLS 8                    // dst cols per recheck block

// ws layout (floats)
#define O_ND    0                                  // fp32 normalized [16384][256]
#define O_HI    (O_ND + T_ALL*NPTS*DD)             // bf16 hi, frag layout (shorts)
#define O_LO    (O_HI + T_ALL*NPTS*DD/2)
#define O_PV1   (O_LO + T_ALL*NPTS*DD/2)           // per (row, colblock) top1
#define O_PI1   (O_PV1 + T1*NPTS*NPB)
#define O_PV2   (O_PI1 + T1*NPTS*NPB)              // per (row, colblock) top2
#define O_BEST  (O_PV2 + T1*NPTS*NPB)              // u64 [14336]
#define O_WL    (O_BEST + T1*NPTS*2)               // int per-t worklists [7][2048]
#define O_CNT   (O_WL + T1*NPTS)                   // int cntT[8]

typedef __attribute__((ext_vector_type(8))) short short8v;   // 8 bf16 (4 VGPR)
typedef __attribute__((ext_vector_type(4))) float float4v;   // MFMA acc

__device__ __forceinline__ unsigned short f2bf(float x) {    // RNE f32->bf16
    unsigned u = __float_as_uint(x);
    return (unsigned short)((u + 0x7FFFu + ((u >> 16) & 1u)) >> 16);
}
__device__ __forceinline__ float bf2f(unsigned short h) {
    return __uint_as_float(((unsigned)h) << 16);
}
// monotone pack: larger value wins; equal value -> smaller idx wins
__device__ __forceinline__ unsigned long long packVI(float v, int idx) {
    unsigned int b = __float_as_uint(v);
    b = (b & 0x80000000u) ? ~b : (b | 0x80000000u);
    return ((unsigned long long)b << 32) | (unsigned int)(NPTS - 1 - idx);
}

// ---------------------------------------------------------------------------
// Kernel 1: normalize rows; emit fp32 nd + bf16 hi/lo in MFMA-frag layout.
// Frag layout per 16-row group: [kstep 0..7][lane 0..63][e 0..7] shorts where
// lane=(row&15)+16*((k>>2)&3), e=4*((k>>4)&1)+(k&3), k=kstep*32+kk. A and B
// use the SAME map, so any HW k-permutation cancels in the dot product.
// Also zeroes the per-t recheck counters.
// ---------------------------------------------------------------------------
__global__ __launch_bounds__(256) void prep_kernel(const float* __restrict__ desc,
                                                   float* __restrict__ nd,
                                                   ushort* __restrict__ ghi,
                                                   ushort* __restrict__ glo,
                                                   int* __restrict__ cntT) {
    int gid  = blockIdx.x * 256 + threadIdx.x;
    if (gid < 8) cntT[gid] = 0;
    int row  = gid >> 6;
    int lane = gid & 63;
    float4 v = reinterpret_cast<const float4*>(desc)[(size_t)row * (DD / 4) + lane];
    float s = v.x * v.x + v.y * v.y + v.z * v.z + v.w * v.w;
#pragma unroll
    for (int off = 32; off >= 1; off >>= 1) s += __shfl_xor(s, off, 64);
    float n = fmaxf(sqrtf(s), 1e-8f);
    float4 o = make_float4(v.x / n, v.y / n, v.z / n, v.w / n);
    reinterpret_cast<float4*>(nd)[(size_t)row * (DD / 4) + lane] = o;

    ushort4 h, l;
    h.x = f2bf(o.x); l.x = f2bf(o.x - bf2f(h.x));
    h.y = f2bf(o.y); l.y = f2bf(o.y - bf2f(h.y));
    h.z = f2bf(o.z); l.z = f2bf(o.z - bf2f(h.z));
    h.w = f2bf(o.w); l.w = f2bf(o.w - bf2f(h.w));
    // k = 4*lane + j: kstep=lane>>3, sub=lane&3, eb=(lane>>2)&1, e=4*eb+j
    size_t base = ((size_t)(row >> 4) * 8 + (lane >> 3)) * 512
                + (size_t)((row & 15) + 16 * (lane & 3)) * 8 + 4 * ((lane >> 2) & 1);
    *reinterpret_cast<ushort4*>(ghi + base) = h;
    *reinterpret_cast<ushort4*>(glo + base) = l;
}

// ---------------------------------------------------------------------------
// Kernel 2: bf16 MFMA match. Block = 256 thr (4 waves), tile 128x128,
// K_eff = 768 (3 passes: hi*hi, hi*lo, lo*hi), BK=32 per round, 24 rounds.
// LDS slot swizzle: logical 16B-slot x of rowgroup g stored at x ^ (g&3).
// R10's linear layout put all 64 staging-write lanes into 8 banks
// (g*1024 % 128 == 0) -> 1.65e7 conflict cycles/dispatch = 384 cyc/round,
// equal to the round's whole MFMA time. Swizzled writes hit all 8 bank-sets
// evenly; frag reads (slot = l ^ f) stay a 0..63 permutation = BW minimum.
// ---------------------------------------------------------------------------
__global__ __launch_bounds__(256) void match_kernel(const ushort* __restrict__ ghi,
                                                    const ushort* __restrict__ glo,
                                                    float* __restrict__ pV1,
                                                    int* __restrict__ pI1,
                                                    float* __restrict__ pV2) {
    __shared__ __align__(16) ushort sAB[8192];     // sA 8KB | sB 8KB
    const int bid = blockIdx.x;                    // ((t*16)+rb)*16 + cb
    const int cb  = bid & 15;
    const int rb  = (bid >> 4) & 15;
    const int t   = bid >> 8;
    const int tid = threadIdx.x;
    const int w   = tid >> 6;                      // wave 0..3
    const int l   = tid & 63;
    const int wr  = w >> 1;                        // row quadrant
    const int wc  = w & 1;                         // col quadrant

    // staging role: threads 0..127 -> A, 128..255 -> B; 64B per thread/round
    const int half = tid >> 7;
    const int g    = (tid & 127) >> 4;             // row/col group 0..7
    const int c    = tid & 15;                     // 64B chunk
    const int rg   = half ? ((t + 1) * 128 + cb * 8 + g)
                          : (t * 128 + rb * 8 + g);

    uint4 pr0, pr1, pr2, pr3;
    auto issue = [&](int rd) {
        bool useLo = half ? (rd >= 8 && rd < 16) : (rd >= 16);
        const ushort* bp = useLo ? glo : ghi;
        const ushort* sp = bp + (((size_t)rg * 8 + (rd & 7)) << 9) + (c << 5);
        const uint4* u = reinterpret_cast<const uint4*>(sp);
        pr0 = u[0]; pr1 = u[1]; pr2 = u[2]; pr3 = u[3];
    };
    auto stage = [&]() {
        char* base = (char*)sAB + (half ? 8192 : 0) + (g << 10);
        const int gs = g & 3;
        *reinterpret_cast<uint4*>(base + ((((c << 2) + 0) ^ gs) << 4)) = pr0;
        *reinterpret_cast<uint4*>(base + ((((c << 2) + 1) ^ gs) << 4)) = pr1;
        *reinterpret_cast<uint4*>(base + ((((c << 2) + 2) ^ gs) << 4)) = pr2;
        *reinterpret_cast<uint4*>(base + ((((c << 2) + 3) ^ gs) << 4)) = pr3;
    };

    float4v acc[4][4];
#pragma unroll
    for (int fa = 0; fa < 4; ++fa)
#pragma unroll
        for (int fb = 0; fb < 4; ++fb) acc[fa][fb] = (float4v){0.f, 0.f, 0.f, 0.f};

    issue(0);
#pragma unroll 1
    for (int rd = 0; rd < 24; ++rd) {
        stage();
        __syncthreads();                           // tiles ready
        if (rd < 23) issue(rd + 1);                // loads fly under MFMA
        short8v af[4], bfr[4];
#pragma unroll
        for (int f = 0; f < 4; ++f) {
            // rowgroup wr*4+f has (rowgroup&3)==f -> stored slot = l ^ f
            af[f]  = *reinterpret_cast<const short8v*>(
                (char*)sAB + ((wr * 4 + f) << 10) + ((l ^ f) << 4));
            bfr[f] = *reinterpret_cast<const short8v*>(
                (char*)sAB + 8192 + ((wc * 4 + f) << 10) + ((l ^ f) << 4));
        }
#pragma unroll
        for (int fa = 0; fa < 4; ++fa)
#pragma unroll
            for (int fb = 0; fb < 4; ++fb)
                acc[fa][fb] = __builtin_amdgcn_mfma_f32_16x16x32_bf16(
                    af[fa], bfr[fb], acc[fa][fb], 0, 0, 0);
        __syncthreads();                           // reads done before re-stage
    }

    // ---- epilogue: D row = wr*64+fa*16+4*(l>>4)+r, col = wc*64+fb*16+(l&15)
    float* exV1 = (float*)sAB;                     // [2][128]
    int*   exI1 = (int*)sAB + 256;
    float* exV2 = (float*)sAB + 512;
    __syncthreads();
#pragma unroll
    for (int fa = 0; fa < 4; ++fa) {
#pragma unroll
        for (int r = 0; r < 4; ++r) {
            float v1 = -3.0e38f, v2 = -3.0e38f; int i1 = 0;
#pragma unroll
            for (int fb = 0; fb < 4; ++fb) {
                float x  = acc[fa][fb][r];
                int  col = cb * 128 + wc * 64 + fb * 16 + (l & 15);
                if (x > v1) { v2 = v1; v1 = x; i1 = col; }
                else        { v2 = fmaxf(v2, x); }
            }
#pragma unroll
            for (int m = 1; m <= 8; m <<= 1) {     // 16-lane butterfly
                float ov1 = __shfl_xor(v1, m);
                int   oi1 = __shfl_xor(i1, m);
                float ov2 = __shfl_xor(v2, m);
                bool take = (ov1 > v1) || (ov1 == v1 && oi1 < i1);
                float nv2 = take ? fmaxf(ov2, v1) : fmaxf(v2, ov1);
                v1 = take ? ov1 : v1;  i1 = take ? oi1 : i1;  v2 = nv2;
            }
            if ((l & 15) == 0) {
                int rloc = wr * 64 + fa * 16 + (l >> 4) * 4 + r;
                exV1[wc * 128 + rloc] = v1;
                exI1[wc * 128 + rloc] = i1;
                exV2[wc * 128 + rloc] = v2;
            }
        }
    }
    __syncthreads();
    if (tid < 128) {
        float v1 = exV1[tid];       int i1 = exI1[tid];       float v2 = exV2[tid];
        float b1 = exV1[128 + tid]; int bi = exI1[128 + tid]; float b2 = exV2[128 + tid];
        bool take = (b1 > v1) || (b1 == v1 && bi < i1);
        float nv2 = take ? fmaxf(b2, v1) : fmaxf(v2, b1);
        if (take) { v1 = b1; i1 = bi; }
        int idx = (t * NPTS + rb * 128 + tid) * NPB + cb;
        pV1[idx] = v1; pI1[idx] = i1; pV2[idx] = nv2;
    }
}

// ---------------------------------------------------------------------------
// Kernel 3: global top-2 margin per row; near-ties -> per-t worklist; safe
// rows commit approx best (value error <= 4.8e-5 << bf16-granular bar).
// ---------------------------------------------------------------------------
__global__ __launch_bounds__(256) void margin_kernel(const float* __restrict__ pV1,
                                                     const int* __restrict__ pI1,
                                                     const float* __restrict__ pV2,
                                                     unsigned long long* __restrict__ best,
                                                     int* __restrict__ wlT,
                                                     int* __restrict__ cntT) {
    int r = blockIdx.x * 256 + threadIdx.x;        // 0..14335
    int t = r >> 11;
    float v1 = -3.0e38f, v2 = -3.0e38f; int i1 = 0;
#pragma unroll
    for (int cbk = 0; cbk < NPB; ++cbk) {          // ascending -> first-occurrence
        int idx = r * NPB + cbk;
        float a1 = pV1[idx]; int ai = pI1[idx]; float a2 = pV2[idx];
        if (a1 > v1) { v2 = fmaxf(v1, a2); v1 = a1; i1 = ai; }
        else         { v2 = fmaxf(v2, a1); }
    }
    if (v1 - v2 < MARGIN_THR) {
        best[r] = 0ull;
        int slot = atomicAdd(&cntT[t], 1);
        wlT[t * NPTS + slot] = r & (NPTS - 1);     // row within frame
    } else {
        best[r] = packVI(v1, i1);
    }
}

// ---------------------------------------------------------------------------
// Kernel 4: exact fp32 rescore, loop-inverted: block = (t, 8-col slab).
// Stage the slab once in LDS, loop that t's flagged rows (~1-2% of rows).
// R10's row-major recheck re-fetched the 2MB dst frame per flagged row with
// 64-distinct-row wave loads (4x overfetch); this fetches each slab once.
// Order-independent atomicMax merge -> deterministic.
// ---------------------------------------------------------------------------
__global__ __launch_bounds__(256) void recheck_kernel(const float* __restrict__ nd,
                                                      const int* __restrict__ wlT,
                                                      const int* __restrict__ cntT,
                                                      unsigned long long* __restrict__ best) {
    __shared__ float dstS[DD][RC_COLS + 1];        // 9.2 KB, transposed slab
    __shared__ float sSrc[DD];
    __shared__ float red[32][RC_COLS + 1];
    const int t   = blockIdx.x >> 8;               // grid = 7 * 256
    const int cc  = blockIdx.x & 255;
    const int nr  = cntT[t];
    if (nr == 0) return;
    const int tid  = threadIdx.x;
    const int col0 = cc * RC_COLS;

    {   // stage 8 dst cols (1 KB each), transposed for bank-even reads
        const int col = tid >> 5;                  // 0..7
        const int k8  = tid & 31;                  // 2 float4 per thread
        const float* dp = nd + ((size_t)((t + 1) * NPTS) + col0 + col) * DD;
#pragma unroll
        for (int j = 0; j < 2; ++j) {
            float4 v = reinterpret_cast<const float4*>(dp)[k8 * 2 + j];
            int k = (k8 * 2 + j) * 4;
            dstS[k + 0][col] = v.x; dstS[k + 1][col] = v.y;
            dstS[k + 2][col] = v.z; dstS[k + 3][col] = v.w;
        }
    }
    const int tx = tid & 7;                        // col
    const int ty = tid >> 3;                       // 32 k-segments of 8
#pragma unroll 1
    for (int ri = 0; ri < nr; ++ri) {
        const int row = wlT[t * NPTS + ri];
        const int r   = t * NPTS + row;
        __syncthreads();                           // dstS ready / sSrc+red free
        if (tid < 64)
            reinterpret_cast<float4*>(sSrc)[tid] =
                reinterpret_cast<const float4*>(nd + ((size_t)(t * NPTS) + row) * DD)[tid];
        __syncthreads();
        float p = 0.f;
#pragma unroll
        for (int j = 0; j < 8; ++j)
            p = fmaf(sSrc[ty * 8 + j], dstS[ty * 8 + j][tx], p);
        red[ty][tx] = p;
        __syncthreads();
        if (tid < 64) {
            const int s = tid >> 3, x = tid & 7;
            float q = red[s][x] + red[s + 8][x] + red[s + 16][x] + red[s + 24][x];
            q += __shfl_xor(q, 8); q += __shfl_xor(q, 16); q += __shfl_xor(q, 32);
            float bv = q; int bi = col0 + x;       // every lane: its col's sum
#pragma unroll
            for (int m = 1; m <= 4; m <<= 1) {     // top-1 across the 8 cols
                float ov = __shfl_xor(bv, m);
                int   oi = __shfl_xor(bi, m);
                if (ov > bv || (ov == bv && oi < bi)) { bv = ov; bi = oi; }
            }
            if (tid == 0) atomicMax(&best[r], packVI(bv, bi));
        }
    }
}

// ---------------------------------------------------------------------------
// Kernel 5: unpack best[], gather matched points, write outputs.
// ---------------------------------------------------------------------------
__global__ __launch_bounds__(256) void final_kernel(const unsigned long long* __restrict__ best,
                                                    const float* __restrict__ pts,
                                                    float* __restrict__ out) {
    int r = blockIdx.x * 256 + threadIdx.x;
    int t = r >> 11;
    unsigned long long p = best[r];
    int idx = NPTS - 1 - (int)(p & 0xFFFFFFFFull);
    unsigned int b = (unsigned int)(p >> 32);
    b = (b & 0x80000000u) ? (b & 0x7FFFFFFFu) : ~b;
    out[(size_t)T1 * NPTS * 2 + r] = __uint_as_float(b);
    const float* q = pts + ((size_t)((t + 1) * NPTS) + idx) * 2;
    out[(size_t)r * 2 + 0] = q[0];
    out[(size_t)r * 2 + 1] = q[1];
}

// ---------------------------------------------------------------------------
extern "C" void kernel_launch(void* const* d_in, const int* in_sizes, int n_in,
                              void* d_out, int out_size, void* d_ws, size_t ws_size,
                              hipStream_t stream) {
    const float* desc = (const float*)d_in[0];     // [8, 2048, 256] fp32
    const float* pts  = (const float*)d_in[1];     // [8, 2048, 2]   fp32
    float* ws = (float*)d_ws;
    float* nd  = ws + O_ND;
    ushort* ghi = (ushort*)(ws + O_HI);
    ushort* glo = (ushort*)(ws + O_LO);
    float* pV1 = ws + O_PV1;
    int*   pI1 = (int*)(ws + O_PI1);
    float* pV2 = ws + O_PV2;
    unsigned long long* best = (unsigned long long*)(ws + O_BEST);
    int* wlT  = (int*)(ws + O_WL);
    int* cntT = (int*)(ws + O_CNT);

    prep_kernel<<<(T_ALL * NPTS) / 4, 256, 0, stream>>>(desc, nd, ghi, glo, cntT);
    match_kernel<<<T1 * 16 * 16, 256, 0, stream>>>(ghi, glo, pV1, pI1, pV2);
    margin_kernel<<<(T1 * NPTS) / 256, 256, 0, stream>>>(pV1, pI1, pV2, best, wlT, cntT);
    recheck_kernel<<<T1 * 256, 256, 0, stream>>>(nd, wlT, cntT, best);
    final_kernel<<<(T1 * NPTS) / 256, 256, 0, stream>>>(best, pts, (float*)d_out);
}

// Round 12
// 143.019 us; speedup vs baseline: 1.1922x; 1.1922x over previous
//
#include <hip/hip_runtime.h>

// Problem constants (fixed by setup_inputs: T=8, N=2048, D=256)
#define T_ALL 8
#define T1    7
#define NPTS  2048
#define DD    256
#define NPB   16                     // 128-col blocks per frame
#define MARGIN_THR 2.0e-4f           // 2x the 9.6e-5 rigorous (C-S) margin bound
#define RC_COLS 8                    // dst cols per recheck block

// ws layout (floats)
#define O_ND    0                                  // fp32 normalized [16384][256]
#define O_HI    (O_ND + T_ALL*NPTS*DD)             // bf16 hi, frag layout (shorts)
#define O_LO    (O_HI + T_ALL*NPTS*DD/2)
#define O_PV1   (O_LO + T_ALL*NPTS*DD/2)           // per (row, colblock) top1
#define O_PI1   (O_PV1 + T1*NPTS*NPB)
#define O_PV2   (O_PI1 + T1*NPTS*NPB)              // per (row, colblock) top2
#define O_BEST  (O_PV2 + T1*NPTS*NPB)              // u64 [14336]
#define O_WL    (O_BEST + T1*NPTS*2)               // int per-t worklists [7][2048]
#define O_CNT   (O_WL + T1*NPTS)                   // int cntT[8]

typedef __attribute__((ext_vector_type(8))) short short8v;   // 8 bf16 (4 VGPR)
typedef __attribute__((ext_vector_type(4))) float float4v;   // MFMA acc

__device__ __forceinline__ unsigned short f2bf(float x) {    // RNE f32->bf16
    unsigned u = __float_as_uint(x);
    return (unsigned short)((u + 0x7FFFu + ((u >> 16) & 1u)) >> 16);
}
__device__ __forceinline__ float bf2f(unsigned short h) {
    return __uint_as_float(((unsigned)h) << 16);
}
// monotone pack: larger value wins; equal value -> smaller idx wins
__device__ __forceinline__ unsigned long long packVI(float v, int idx) {
    unsigned int b = __float_as_uint(v);
    b = (b & 0x80000000u) ? ~b : (b | 0x80000000u);
    return ((unsigned long long)b << 32) | (unsigned int)(NPTS - 1 - idx);
}

// ---------------------------------------------------------------------------
// Kernel 1: normalize rows; emit fp32 nd + bf16 hi/lo in MFMA-frag layout.
// Frag layout per (16-row group, 32-k step): a contiguous 1KB tile; within it
// lane=(row&15)+16*((k>>2)&3), e=4*((k>>4)&1)+(k&3). A and B use the SAME
// map, so any HW k-permutation cancels in the dot product. 1KB tiles are
// lane-contiguous (lane*16B) == global_load_lds's required dest form.
// ---------------------------------------------------------------------------
__global__ __launch_bounds__(256) void prep_kernel(const float* __restrict__ desc,
                                                   float* __restrict__ nd,
                                                   ushort* __restrict__ ghi,
                                                   ushort* __restrict__ glo,
                                                   int* __restrict__ cntT) {
    int gid  = blockIdx.x * 256 + threadIdx.x;
    if (gid < 8) cntT[gid] = 0;
    int row  = gid >> 6;
    int lane = gid & 63;
    float4 v = reinterpret_cast<const float4*>(desc)[(size_t)row * (DD / 4) + lane];
    float s = v.x * v.x + v.y * v.y + v.z * v.z + v.w * v.w;
#pragma unroll
    for (int off = 32; off >= 1; off >>= 1) s += __shfl_xor(s, off, 64);
    float n = fmaxf(sqrtf(s), 1e-8f);
    float4 o = make_float4(v.x / n, v.y / n, v.z / n, v.w / n);
    reinterpret_cast<float4*>(nd)[(size_t)row * (DD / 4) + lane] = o;

    ushort4 h, l;
    h.x = f2bf(o.x); l.x = f2bf(o.x - bf2f(h.x));
    h.y = f2bf(o.y); l.y = f2bf(o.y - bf2f(h.y));
    h.z = f2bf(o.z); l.z = f2bf(o.z - bf2f(h.z));
    h.w = f2bf(o.w); l.w = f2bf(o.w - bf2f(h.w));
    // k = 4*lane + j: kstep=lane>>3, sub=lane&3, eb=(lane>>2)&1, e=4*eb+j
    size_t base = ((size_t)(row >> 4) * 8 + (lane >> 3)) * 512
                + (size_t)((row & 15) + 16 * (lane & 3)) * 8 + 4 * ((lane >> 2) & 1);
    *reinterpret_cast<ushort4*>(ghi + base) = h;
    *reinterpret_cast<ushort4*>(glo + base) = l;
}

// ---------------------------------------------------------------------------
// Kernel 2: bf16 MFMA match, FUSED hi/lo. Block = 256 thr (4 waves), tile
// 128x128. Per 32-k round: stage a_hi|a_lo|b_hi|b_lo (32 KB) via
// global_load_lds (wave w DMAs tensor w's 8 tiles: no staging regs, no VALU
// address work); each wave reads its quadrant frags ONCE and fires the
// 3 correction combos (hh, hl, lh) into the SAME accumulator -> 8 rounds,
// 16 barriers (was 24 rounds / 48 barriers / 1.5x the LDS traffic in R10/11).
// ---------------------------------------------------------------------------
__global__ __launch_bounds__(256) void match_kernel(const ushort* __restrict__ ghi,
                                                    const ushort* __restrict__ glo,
                                                    float* __restrict__ pV1,
                                                    int* __restrict__ pI1,
                                                    float* __restrict__ pV2) {
    __shared__ __align__(16) ushort sAB[16384];    // 32KB: aH|aL|bH|bL, 8KB each
    const int bid = blockIdx.x;                    // ((t*16)+rb)*16 + cb
    const int cb  = bid & 15;
    const int rb  = (bid >> 4) & 15;
    const int t   = bid >> 8;
    const int tid = threadIdx.x;
    const int w   = tid >> 6;                      // wave 0..3
    const int l   = tid & 63;
    const int wr  = w >> 1;                        // row quadrant
    const int wc  = w & 1;                         // col quadrant

    // DMA staging: wave w owns tensor w (0=a_hi, 1=a_lo, 2=b_hi, 3=b_lo)
    const ushort* tsrc = (w & 1) ? glo : ghi;
    const int rgbase = (w < 2) ? (t * 128 + rb * 8)
                               : ((t + 1) * 128 + cb * 8);

    float4v acc[4][4];
#pragma unroll
    for (int fa = 0; fa < 4; ++fa)
#pragma unroll
        for (int fb = 0; fb < 4; ++fb) acc[fa][fb] = (float4v){0.f, 0.f, 0.f, 0.f};

#pragma unroll 1
    for (int rd = 0; rd < 8; ++rd) {
        // ---- issue this round's 8 tile-DMAs (1KB each, lane-contiguous) ----
#pragma unroll
        for (int i = 0; i < 8; ++i) {
            const ushort* gp = tsrc + (((size_t)(rgbase + i) * 8 + rd) << 9) + (l << 3);
            __builtin_amdgcn_global_load_lds(
                (const __attribute__((address_space(1))) unsigned int*)gp,
                (__attribute__((address_space(3))) unsigned int*)&sAB[(w * 8 + i) << 9],
                16, 0, 0);
        }
        __syncthreads();                           // own vmcnt drained + all waves
        // ---- fused compute: 16 b128 reads -> 48 MFMAs ----
        short8v bh[4], bl[4];
#pragma unroll
        for (int f = 0; f < 4; ++f) {
            bh[f] = *reinterpret_cast<const short8v*>(&sAB[((16 + wc * 4 + f) << 9) + l * 8]);
            bl[f] = *reinterpret_cast<const short8v*>(&sAB[((24 + wc * 4 + f) << 9) + l * 8]);
        }
#pragma unroll
        for (int fa = 0; fa < 4; ++fa) {
            short8v ah = *reinterpret_cast<const short8v*>(&sAB[(((wr * 4 + fa)) << 9) + l * 8]);
            short8v al = *reinterpret_cast<const short8v*>(&sAB[((8 + wr * 4 + fa) << 9) + l * 8]);
#pragma unroll
            for (int fb = 0; fb < 4; ++fb)
                acc[fa][fb] = __builtin_amdgcn_mfma_f32_16x16x32_bf16(ah, bh[fb], acc[fa][fb], 0, 0, 0);
#pragma unroll
            for (int fb = 0; fb < 4; ++fb)
                acc[fa][fb] = __builtin_amdgcn_mfma_f32_16x16x32_bf16(ah, bl[fb], acc[fa][fb], 0, 0, 0);
#pragma unroll
            for (int fb = 0; fb < 4; ++fb)
                acc[fa][fb] = __builtin_amdgcn_mfma_f32_16x16x32_bf16(al, bh[fb], acc[fa][fb], 0, 0, 0);
        }
        __syncthreads();                           // all reads done before next DMA
    }

    // ---- epilogue: D row = wr*64+fa*16+4*(l>>4)+r, col = wc*64+fb*16+(l&15)
    float* exV1 = (float*)sAB;                     // [2][128]
    int*   exI1 = (int*)sAB + 256;
    float* exV2 = (float*)sAB + 512;
#pragma unroll
    for (int fa = 0; fa < 4; ++fa) {
#pragma unroll
        for (int r = 0; r < 4; ++r) {
            float v1 = -3.0e38f, v2 = -3.0e38f; int i1 = 0;
#pragma unroll
            for (int fb = 0; fb < 4; ++fb) {
                float x  = acc[fa][fb][r];
                int  col = cb * 128 + wc * 64 + fb * 16 + (l & 15);
                if (x > v1) { v2 = v1; v1 = x; i1 = col; }
                else        { v2 = fmaxf(v2, x); }
            }
#pragma unroll
            for (int m = 1; m <= 8; m <<= 1) {     // 16-lane butterfly
                float ov1 = __shfl_xor(v1, m);
                int   oi1 = __shfl_xor(i1, m);
                float ov2 = __shfl_xor(v2, m);
                bool take = (ov1 > v1) || (ov1 == v1 && oi1 < i1);
                float nv2 = take ? fmaxf(ov2, v1) : fmaxf(v2, ov1);
                v1 = take ? ov1 : v1;  i1 = take ? oi1 : i1;  v2 = nv2;
            }
            if ((l & 15) == 0) {
                int rloc = wr * 64 + fa * 16 + (l >> 4) * 4 + r;
                exV1[wc * 128 + rloc] = v1;
                exI1[wc * 128 + rloc] = i1;
                exV2[wc * 128 + rloc] = v2;
            }
        }
    }
    __syncthreads();
    if (tid < 128) {
        float v1 = exV1[tid];       int i1 = exI1[tid];       float v2 = exV2[tid];
        float b1 = exV1[128 + tid]; int bi = exI1[128 + tid]; float b2 = exV2[128 + tid];
        bool take = (b1 > v1) || (b1 == v1 && bi < i1);
        float nv2 = take ? fmaxf(b2, v1) : fmaxf(v2, b1);
        if (take) { v1 = b1; i1 = bi; }
        int idx = (t * NPTS + rb * 128 + tid) * NPB + cb;
        pV1[idx] = v1; pI1[idx] = i1; pV2[idx] = nv2;
    }
}

// ---------------------------------------------------------------------------
// Kernel 3: global top-2 margin per row; near-ties -> per-t worklist; safe
// rows commit approx best (value error <= 4.8e-5 << bf16-granular bar).
// ---------------------------------------------------------------------------
__global__ __launch_bounds__(256) void margin_kernel(const float* __restrict__ pV1,
                                                     const int* __restrict__ pI1,
                                                     const float* __restrict__ pV2,
                                                     unsigned long long* __restrict__ best,
                                                     int* __restrict__ wlT,
                                                     int* __restrict__ cntT) {
    int r = blockIdx.x * 256 + threadIdx.x;        // 0..14335
    int t = r >> 11;
    float v1 = -3.0e38f, v2 = -3.0e38f; int i1 = 0;
#pragma unroll
    for (int cbk = 0; cbk < NPB; ++cbk) {          // ascending -> first-occurrence
        int idx = r * NPB + cbk;
        float a1 = pV1[idx]; int ai = pI1[idx]; float a2 = pV2[idx];
        if (a1 > v1) { v2 = fmaxf(v1, a2); v1 = a1; i1 = ai; }
        else         { v2 = fmaxf(v2, a1); }
    }
    if (v1 - v2 < MARGIN_THR) {
        best[r] = 0ull;
        int slot = atomicAdd(&cntT[t], 1);
        wlT[t * NPTS + slot] = r & (NPTS - 1);     // row within frame
    } else {
        best[r] = packVI(v1, i1);
    }
}

// ---------------------------------------------------------------------------
// Kernel 4: exact fp32 rescore, loop-inverted: block = (t, 8-col slab).
// Stage the slab once in LDS, loop that t's flagged rows (~1-2% of rows).
// Order-independent atomicMax merge -> deterministic.
// ---------------------------------------------------------------------------
__global__ __launch_bounds__(256) void recheck_kernel(const float* __restrict__ nd,
                                                      const int* __restrict__ wlT,
                                                      const int* __restrict__ cntT,
                                                      unsigned long long* __restrict__ best) {
    __shared__ float dstS[DD][RC_COLS + 1];        // 9.2 KB, transposed slab
    __shared__ float sSrc[DD];
    __shared__ float red[32][RC_COLS + 1];
    const int t   = blockIdx.x >> 8;               // grid = 7 * 256
    const int cc  = blockIdx.x & 255;
    const int nr  = cntT[t];
    if (nr == 0) return;
    const int tid  = threadIdx.x;
    const int col0 = cc * RC_COLS;

    {   // stage 8 dst cols (1 KB each), transposed for bank-even reads
        const int col = tid >> 5;                  // 0..7
        const int k8  = tid & 31;                  // 2 float4 per thread
        const float* dp = nd + ((size_t)((t + 1) * NPTS) + col0 + col) * DD;
#pragma unroll
        for (int j = 0; j < 2; ++j) {
            float4 v = reinterpret_cast<const float4*>(dp)[k8 * 2 + j];
            int k = (k8 * 2 + j) * 4;
            dstS[k + 0][col] = v.x; dstS[k + 1][col] = v.y;
            dstS[k + 2][col] = v.z; dstS[k + 3][col] = v.w;
        }
    }
    const int tx = tid & 7;                        // col
    const int ty = tid >> 3;                       // 32 k-segments of 8
#pragma unroll 1
    for (int ri = 0; ri < nr; ++ri) {
        const int row = wlT[t * NPTS + ri];
        const int r   = t * NPTS + row;
        __syncthreads();                           // dstS ready / sSrc+red free
        if (tid < 64)
            reinterpret_cast<float4*>(sSrc)[tid] =
                reinterpret_cast<const float4*>(nd + ((size_t)(t * NPTS) + row) * DD)[tid];
        __syncthreads();
        float p = 0.f;
#pragma unroll
        for (int j = 0; j < 8; ++j)
            p = fmaf(sSrc[ty * 8 + j], dstS[ty * 8 + j][tx], p);
        red[ty][tx] = p;
        __syncthreads();
        if (tid < 64) {
            const int s = tid >> 3, x = tid & 7;
            float q = red[s][x] + red[s + 8][x] + red[s + 16][x] + red[s + 24][x];
            q += __shfl_xor(q, 8); q += __shfl_xor(q, 16); q += __shfl_xor(q, 32);
            float bv = q; int bi = col0 + x;       // every lane: its col's sum
#pragma unroll
            for (int m = 1; m <= 4; m <<= 1) {     // top-1 across the 8 cols
                float ov = __shfl_xor(bv, m);
                int   oi = __shfl_xor(bi, m);
                if (ov > bv || (ov == bv && oi < bi)) { bv = ov; bi = oi; }
            }
            if (tid == 0) atomicMax(&best[r], packVI(bv, bi));
        }
    }
}

// ---------------------------------------------------------------------------
// Kernel 5: unpack best[], gather matched points, write outputs.
// ---------------------------------------------------------------------------
__global__ __launch_bounds__(256) void final_kernel(const unsigned long long* __restrict__ best,
                                                    const float* __restrict__ pts,
                                                    float* __restrict__ out) {
    int r = blockIdx.x * 256 + threadIdx.x;
    int t = r >> 11;
    unsigned long long p = best[r];
    int idx = NPTS - 1 - (int)(p & 0xFFFFFFFFull);
    unsigned int b = (unsigned int)(p >> 32);
    b = (b & 0x80000000u) ? (b & 0x7FFFFFFFu) : ~b;
    out[(size_t)T1 * NPTS * 2 + r] = __uint_as_float(b);
    const float* q = pts + ((size_t)((t + 1) * NPTS) + idx) * 2;
    out[(size_t)r * 2 + 0] = q[0];
    out[(size_t)r * 2 + 1] = q[1];
}

// ---------------------------------------------------------------------------
extern "C" void kernel_launch(void* const* d_in, const int* in_sizes, int n_in,
                              void* d_out, int out_size, void* d_ws, size_t ws_size,
                              hipStream_t stream) {
    const float* desc = (const float*)d_in[0];     // [8, 2048, 256] fp32
    const float* pts  = (const float*)d_in[1];     // [8, 2048, 2]   fp32
    float* ws = (float*)d_ws;
    float* nd  = ws + O_ND;
    ushort* ghi = (ushort*)(ws + O_HI);
    ushort* glo = (ushort*)(ws + O_LO);
    float* pV1 = ws + O_PV1;
    int*   pI1 = (int*)(ws + O_PI1);
    float* pV2 = ws + O_PV2;
    unsigned long long* best = (unsigned long long*)(ws + O_BEST);
    int* wlT  = (int*)(ws + O_WL);
    int* cntT = (int*)(ws + O_CNT);

    prep_kernel<<<(T_ALL * NPTS) / 4, 256, 0, stream>>>(desc, nd, ghi, glo, cntT);
    match_kernel<<<T1 * 16 * 16, 256, 0, stream>>>(ghi, glo, pV1, pI1, pV2);
    margin_kernel<<<(T1 * NPTS) / 256, 256, 0, stream>>>(pV1, pI1, pV2, best, wlT, cntT);
    recheck_kernel<<<T1 * 256, 256, 0, stream>>>(nd, wlT, cntT, best);
    final_kernel<<<(T1 * NPTS) / 256, 256, 0, stream>>>(best, pts, (float*)d_out);
}

// Round 13
// 128.125 us; speedup vs baseline: 1.3308x; 1.1162x over previous
//
#include <hip/hip_runtime.h>

// Problem constants (fixed by setup_inputs: T=8, N=2048, D=256)
#define T_ALL 8
#define T1    7
#define NPTS  2048
#define DD    256
#define NPB   16                     // 128-col blocks per frame
#define MARGIN_THR 2.0e-4f           // 2x the 9.6e-5 rigorous (C-S) margin bound
#define RC_COLS 8                    // dst cols per recheck block
#define RC_ROWS 24                   // src rows staged per recheck batch

// ws layout (floats)
#define O_ND    0                                  // fp32 normalized [16384][256]
#define O_HI    (O_ND + T_ALL*NPTS*DD)             // bf16 hi, frag layout (shorts)
#define O_LO    (O_HI + T_ALL*NPTS*DD/2)
#define O_PV1   (O_LO + T_ALL*NPTS*DD/2)           // per (row, colblock) top1
#define O_PI1   (O_PV1 + T1*NPTS*NPB)
#define O_PV2   (O_PI1 + T1*NPTS*NPB)              // per (row, colblock) top2
#define O_BEST  (O_PV2 + T1*NPTS*NPB)              // u64 [14336]
#define O_WL    (O_BEST + T1*NPTS*2)               // int per-t worklists [7][2048]
#define O_CNT   (O_WL + T1*NPTS)                   // int cntT[8]

typedef __attribute__((ext_vector_type(8))) short short8v;   // 8 bf16 (4 VGPR)
typedef __attribute__((ext_vector_type(4))) float float4v;   // MFMA acc

__device__ __forceinline__ unsigned short f2bf(float x) {    // RNE f32->bf16
    unsigned u = __float_as_uint(x);
    return (unsigned short)((u + 0x7FFFu + ((u >> 16) & 1u)) >> 16);
}
__device__ __forceinline__ float bf2f(unsigned short h) {
    return __uint_as_float(((unsigned)h) << 16);
}
// monotone pack: larger value wins; equal value -> smaller idx wins
__device__ __forceinline__ unsigned long long packVI(float v, int idx) {
    unsigned int b = __float_as_uint(v);
    b = (b & 0x80000000u) ? ~b : (b | 0x80000000u);
    return ((unsigned long long)b << 32) | (unsigned int)(NPTS - 1 - idx);
}

// ---------------------------------------------------------------------------
// Kernel 1: normalize rows; emit fp32 nd + bf16 hi/lo in MFMA-frag layout.
// Frag layout per (16-row group, 32-k step): a contiguous 1KB tile; within it
// lane=(row&15)+16*((k>>2)&3), e=4*((k>>4)&1)+(k&3). A and B use the SAME
// map, so any HW k-permutation cancels in the dot product. 1KB tiles are
// lane-contiguous (lane*16B) == global_load_lds's required dest form.
// ---------------------------------------------------------------------------
__global__ __launch_bounds__(256) void prep_kernel(const float* __restrict__ desc,
                                                   float* __restrict__ nd,
                                                   ushort* __restrict__ ghi,
                                                   ushort* __restrict__ glo,
                                                   int* __restrict__ cntT) {
    int gid  = blockIdx.x * 256 + threadIdx.x;
    if (gid < 8) cntT[gid] = 0;
    int row  = gid >> 6;
    int lane = gid & 63;
    float4 v = reinterpret_cast<const float4*>(desc)[(size_t)row * (DD / 4) + lane];
    float s = v.x * v.x + v.y * v.y + v.z * v.z + v.w * v.w;
#pragma unroll
    for (int off = 32; off >= 1; off >>= 1) s += __shfl_xor(s, off, 64);
    float n = fmaxf(sqrtf(s), 1e-8f);
    float4 o = make_float4(v.x / n, v.y / n, v.z / n, v.w / n);
    reinterpret_cast<float4*>(nd)[(size_t)row * (DD / 4) + lane] = o;

    ushort4 h, l;
    h.x = f2bf(o.x); l.x = f2bf(o.x - bf2f(h.x));
    h.y = f2bf(o.y); l.y = f2bf(o.y - bf2f(h.y));
    h.z = f2bf(o.z); l.z = f2bf(o.z - bf2f(h.z));
    h.w = f2bf(o.w); l.w = f2bf(o.w - bf2f(h.w));
    // k = 4*lane + j: kstep=lane>>3, sub=lane&3, eb=(lane>>2)&1, e=4*eb+j
    size_t base = ((size_t)(row >> 4) * 8 + (lane >> 3)) * 512
                + (size_t)((row & 15) + 16 * (lane & 3)) * 8 + 4 * ((lane >> 2) & 1);
    *reinterpret_cast<ushort4*>(ghi + base) = h;
    *reinterpret_cast<ushort4*>(glo + base) = l;
}

// ---------------------------------------------------------------------------
// Kernel 2: bf16 MFMA match, fused hi/lo + DOUBLE-BUFFERED DMA. Block =
// 256 thr (4 waves), tile 128x128. Per 32-k round: wave w DMAs tensor w
// (a_hi|a_lo|b_hi|b_lo) for round rd+1 into buf^1, then computes round rd
// from buf (48 MFMAs: hh+hl+lh into one accumulator). The end-of-round
// barrier's vmcnt(0) drain thus lands AFTER ~700 cyc of compute has covered
// the DMA flight (R12's single buffer exposed the full 32KB DMA latency
// every round: MfmaUtil 21%, 84us vs the 22us MFMA floor).
// ---------------------------------------------------------------------------
__global__ __launch_bounds__(256) void match_kernel(const ushort* __restrict__ ghi,
                                                    const ushort* __restrict__ glo,
                                                    float* __restrict__ pV1,
                                                    int* __restrict__ pI1,
                                                    float* __restrict__ pV2) {
    __shared__ __align__(16) ushort sAB[2][16384];  // 64KB: 2 x (aH|aL|bH|bL)
    const int bid = blockIdx.x;                    // ((t*16)+rb)*16 + cb
    const int cb  = bid & 15;
    const int rb  = (bid >> 4) & 15;
    const int t   = bid >> 8;
    const int tid = threadIdx.x;
    const int w   = tid >> 6;                      // wave 0..3
    const int l   = tid & 63;
    const int wr  = w >> 1;                        // row quadrant
    const int wc  = w & 1;                         // col quadrant

    // DMA staging: wave w owns tensor w (0=a_hi, 1=a_lo, 2=b_hi, 3=b_lo)
    const ushort* tsrc = (w & 1) ? glo : ghi;
    const int rgbase = (w < 2) ? (t * 128 + rb * 8)
                               : ((t + 1) * 128 + cb * 8);

    auto issue = [&](int rd, int buf) {            // 8 x 1KB tile DMAs
#pragma unroll
        for (int i = 0; i < 8; ++i) {
            const ushort* gp = tsrc + (((size_t)(rgbase + i) * 8 + rd) << 9) + (l << 3);
            __builtin_amdgcn_global_load_lds(
                (const __attribute__((address_space(1))) unsigned int*)gp,
                (__attribute__((address_space(3))) unsigned int*)&sAB[buf][(w * 8 + i) << 9],
                16, 0, 0);
        }
    };

    float4v acc[4][4];
#pragma unroll
    for (int fa = 0; fa < 4; ++fa)
#pragma unroll
        for (int fb = 0; fb < 4; ++fb) acc[fa][fb] = (float4v){0.f, 0.f, 0.f, 0.f};

    issue(0, 0);
    __syncthreads();                               // buf0 published (vmcnt drain)
#pragma unroll 1
    for (int rd = 0; rd < 8; ++rd) {
        const int cur = rd & 1;
        if (rd < 7) issue(rd + 1, cur ^ 1);        // prefetch flies under compute
        const ushort* S = sAB[cur];
        short8v bh[4], bl[4];
#pragma unroll
        for (int f = 0; f < 4; ++f) {
            bh[f] = *reinterpret_cast<const short8v*>(&S[((16 + wc * 4 + f) << 9) + l * 8]);
            bl[f] = *reinterpret_cast<const short8v*>(&S[((24 + wc * 4 + f) << 9) + l * 8]);
        }
#pragma unroll
        for (int fa = 0; fa < 4; ++fa) {
            short8v ah = *reinterpret_cast<const short8v*>(&S[(((wr * 4 + fa)) << 9) + l * 8]);
            short8v al = *reinterpret_cast<const short8v*>(&S[((8 + wr * 4 + fa) << 9) + l * 8]);
#pragma unroll
            for (int fb = 0; fb < 4; ++fb)
                acc[fa][fb] = __builtin_amdgcn_mfma_f32_16x16x32_bf16(ah, bh[fb], acc[fa][fb], 0, 0, 0);
#pragma unroll
            for (int fb = 0; fb < 4; ++fb)
                acc[fa][fb] = __builtin_amdgcn_mfma_f32_16x16x32_bf16(ah, bl[fb], acc[fa][fb], 0, 0, 0);
#pragma unroll
            for (int fb = 0; fb < 4; ++fb)
                acc[fa][fb] = __builtin_amdgcn_mfma_f32_16x16x32_bf16(al, bh[fb], acc[fa][fb], 0, 0, 0);
        }
        __syncthreads();   // reads of buf done + prefetch vmcnt drained -> buf^1 live
    }

    // ---- epilogue: D row = wr*64+fa*16+4*(l>>4)+r, col = wc*64+fb*16+(l&15)
    float* exV1 = (float*)sAB;                     // [2][128]
    int*   exI1 = (int*)sAB + 256;
    float* exV2 = (float*)sAB + 512;
#pragma unroll
    for (int fa = 0; fa < 4; ++fa) {
#pragma unroll
        for (int r = 0; r < 4; ++r) {
            float v1 = -3.0e38f, v2 = -3.0e38f; int i1 = 0;
#pragma unroll
            for (int fb = 0; fb < 4; ++fb) {
                float x  = acc[fa][fb][r];
                int  col = cb * 128 + wc * 64 + fb * 16 + (l & 15);
                if (x > v1) { v2 = v1; v1 = x; i1 = col; }
                else        { v2 = fmaxf(v2, x); }
            }
#pragma unroll
            for (int m = 1; m <= 8; m <<= 1) {     // 16-lane butterfly
                float ov1 = __shfl_xor(v1, m);
                int   oi1 = __shfl_xor(i1, m);
                float ov2 = __shfl_xor(v2, m);
                bool take = (ov1 > v1) || (ov1 == v1 && oi1 < i1);
                float nv2 = take ? fmaxf(ov2, v1) : fmaxf(v2, ov1);
                v1 = take ? ov1 : v1;  i1 = take ? oi1 : i1;  v2 = nv2;
            }
            if ((l & 15) == 0) {
                int rloc = wr * 64 + fa * 16 + (l >> 4) * 4 + r;
                exV1[wc * 128 + rloc] = v1;
                exI1[wc * 128 + rloc] = i1;
                exV2[wc * 128 + rloc] = v2;
            }
        }
    }
    __syncthreads();
    if (tid < 128) {
        float v1 = exV1[tid];       int i1 = exI1[tid];       float v2 = exV2[tid];
        float b1 = exV1[128 + tid]; int bi = exI1[128 + tid]; float b2 = exV2[128 + tid];
        bool take = (b1 > v1) || (b1 == v1 && bi < i1);
        float nv2 = take ? fmaxf(b2, v1) : fmaxf(v2, b1);
        if (take) { v1 = b1; i1 = bi; }
        int idx = (t * NPTS + rb * 128 + tid) * NPB + cb;
        pV1[idx] = v1; pI1[idx] = i1; pV2[idx] = nv2;
    }
}

// ---------------------------------------------------------------------------
// Kernel 3: global top-2 margin per row; near-ties -> per-t worklist; safe
// rows commit approx best (value error <= 4.8e-5 << bf16-granular bar).
// ---------------------------------------------------------------------------
__global__ __launch_bounds__(256) void margin_kernel(const float* __restrict__ pV1,
                                                     const int* __restrict__ pI1,
                                                     const float* __restrict__ pV2,
                                                     unsigned long long* __restrict__ best,
                                                     int* __restrict__ wlT,
                                                     int* __restrict__ cntT) {
    int r = blockIdx.x * 256 + threadIdx.x;        // 0..14335
    int t = r >> 11;
    float v1 = -3.0e38f, v2 = -3.0e38f; int i1 = 0;
#pragma unroll
    for (int cbk = 0; cbk < NPB; ++cbk) {          // ascending -> first-occurrence
        int idx = r * NPB + cbk;
        float a1 = pV1[idx]; int ai = pI1[idx]; float a2 = pV2[idx];
        if (a1 > v1) { v2 = fmaxf(v1, a2); v1 = a1; i1 = ai; }
        else         { v2 = fmaxf(v2, a1); }
    }
    if (v1 - v2 < MARGIN_THR) {
        best[r] = 0ull;
        int slot = atomicAdd(&cntT[t], 1);
        wlT[t * NPTS + slot] = r & (NPTS - 1);     // row within frame
    } else {
        best[r] = packVI(v1, i1);
    }
}

// ---------------------------------------------------------------------------
// Kernel 4: exact fp32 rescore, loop-inverted + WAVE-PARALLEL rows.
// Block = (t, 8-col slab). Stage the dst slab + a batch of <=24 flagged src
// rows (conflict-free [*][8][33] layouts), then wave w processes rows
// w, w+4, ... independently -- no per-row barriers (R11/12 ran 3 barriers
// x nr rows serially). Lane split: col = l&7, kseg = l>>3; shfl-reduce k,
// then top-1 over the 8 cols; one atomicMax per row per slab.
// ---------------------------------------------------------------------------
__global__ __launch_bounds__(256) void recheck_kernel(const float* __restrict__ nd,
                                                      const int* __restrict__ wlT,
                                                      const int* __restrict__ cntT,
                                                      unsigned long long* __restrict__ best) {
    __shared__ float dstS[RC_COLS][8][33];         // 8.25 KB  [col][kseg][k]
    __shared__ float srcS[RC_ROWS][8][33];         // 24.75 KB [row][kseg][k]
    const int t   = blockIdx.x >> 8;               // grid = 7 * 256
    const int cc  = blockIdx.x & 255;
    const int nr  = cntT[t];
    if (nr == 0) return;
    const int tid  = threadIdx.x;
    const int w    = tid >> 6;
    const int l    = tid & 63;
    const int col0 = cc * RC_COLS;

    {   // stage 8 dst cols: thread col=tid>>5, 2 float4 (8 floats) each
        const int col = tid >> 5;
        const int k8  = tid & 31;
        const float* dp = nd + ((size_t)((t + 1) * NPTS) + col0 + col) * DD;
#pragma unroll
        for (int j = 0; j < 2; ++j) {
            float4 v = reinterpret_cast<const float4*>(dp)[k8 * 2 + j];
            int k = (k8 * 2 + j) * 4;
            dstS[col][k >> 5][k & 31]       = v.x;
            dstS[col][(k+1) >> 5][(k+1)&31] = v.y;
            dstS[col][(k+2) >> 5][(k+2)&31] = v.z;
            dstS[col][(k+3) >> 5][(k+3)&31] = v.w;
        }
    }

#pragma unroll 1
    for (int base = 0; base < nr; base += RC_ROWS) {
        const int nb = min(RC_ROWS, nr - base);
        __syncthreads();                           // srcS free (and dstS ready, 1st pass)
        for (int idx = tid; idx < nb * 64; idx += 256) {
            const int ri = idx >> 6, ln = idx & 63;
            const int row = wlT[t * NPTS + base + ri];
            float4 v = reinterpret_cast<const float4*>(
                nd + ((size_t)(t * NPTS) + row) * DD)[ln];
            int k = ln * 4;
            srcS[ri][k >> 5][k & 31]       = v.x;
            srcS[ri][(k+1) >> 5][(k+1)&31] = v.y;
            srcS[ri][(k+2) >> 5][(k+2)&31] = v.z;
            srcS[ri][(k+3) >> 5][(k+3)&31] = v.w;
        }
        __syncthreads();                           // batch staged

        const int colx = l & 7, ks = l >> 3;
#pragma unroll 1
        for (int ri = w; ri < nb; ri += 4) {       // waves independent
            const int row = wlT[t * NPTS + base + ri];
            const int r   = t * NPTS + row;
            float p = 0.f;
#pragma unroll
            for (int k = 0; k < 32; ++k)
                p = fmaf(srcS[ri][ks][k], dstS[colx][ks][k], p);
            p += __shfl_xor(p, 8); p += __shfl_xor(p, 16); p += __shfl_xor(p, 32);
            float bv = p; int bi = col0 + colx;
#pragma unroll
            for (int m = 1; m <= 4; m <<= 1) {     // top-1 across 8 cols
                float ov = __shfl_xor(bv, m);
                int   oi = __shfl_xor(bi, m);
                if (ov > bv || (ov == bv && oi < bi)) { bv = ov; bi = oi; }
            }
            if (l == 0) atomicMax(&best[r], packVI(bv, bi));
        }
    }
}

// ---------------------------------------------------------------------------
// Kernel 5: unpack best[], gather matched points, write outputs.
// ---------------------------------------------------------------------------
__global__ __launch_bounds__(256) void final_kernel(const unsigned long long* __restrict__ best,
                                                    const float* __restrict__ pts,
                                                    float* __restrict__ out) {
    int r = blockIdx.x * 256 + threadIdx.x;
    int t = r >> 11;
    unsigned long long p = best[r];
    int idx = NPTS - 1 - (int)(p & 0xFFFFFFFFull);
    unsigned int b = (unsigned int)(p >> 32);
    b = (b & 0x80000000u) ? (b & 0x7FFFFFFFu) : ~b;
    out[(size_t)T1 * NPTS * 2 + r] = __uint_as_float(b);
    const float* q = pts + ((size_t)((t + 1) * NPTS) + idx) * 2;
    out[(size_t)r * 2 + 0] = q[0];
    out[(size_t)r * 2 + 1] = q[1];
}

// ---------------------------------------------------------------------------
extern "C" void kernel_launch(void* const* d_in, const int* in_sizes, int n_in,
                              void* d_out, int out_size, void* d_ws, size_t ws_size,
                              hipStream_t stream) {
    const float* desc = (const float*)d_in[0];     // [8, 2048, 256] fp32
    const float* pts  = (const float*)d_in[1];     // [8, 2048, 2]   fp32
    float* ws = (float*)d_ws;
    float* nd  = ws + O_ND;
    ushort* ghi = (ushort*)(ws + O_HI);
    ushort* glo = (ushort*)(ws + O_LO);
    float* pV1 = ws + O_PV1;
    int*   pI1 = (int*)(ws + O_PI1);
    float* pV2 = ws + O_PV2;
    unsigned long long* best = (unsigned long long*)(ws + O_BEST);
    int* wlT  = (int*)(ws + O_WL);
    int* cntT = (int*)(ws + O_CNT);

    prep_kernel<<<(T_ALL * NPTS) / 4, 256, 0, stream>>>(desc, nd, ghi, glo, cntT);
    match_kernel<<<T1 * 16 * 16, 256, 0, stream>>>(ghi, glo, pV1, pI1, pV2);
    margin_kernel<<<(T1 * NPTS) / 256, 256, 0, stream>>>(pV1, pI1, pV2, best, wlT, cntT);
    recheck_kernel<<<T1 * 256, 256, 0, stream>>>(nd, wlT, cntT, best);
    final_kernel<<<(T1 * NPTS) / 256, 256, 0, stream>>>(best, pts, (float*)d_out);
}

// Round 14
// 126.851 us; speedup vs baseline: 1.3442x; 1.0100x over previous
//
#include <hip/hip_runtime.h>

// Problem constants (fixed by setup_inputs: T=8, N=2048, D=256)
#define T_ALL 8
#define T1    7
#define NPTS  2048
#define DD    256
#define NPB   16                     // 128-col blocks per frame
#define MARGIN_THR 2.0e-4f           // 2x the 9.6e-5 rigorous (C-S) margin bound
#define RC_COLS 8                    // dst cols per recheck block
#define RC_ROWS 24                   // src rows staged per recheck batch

// ws layout (floats)
#define O_ND    0                                  // fp32 normalized [16384][256]
#define O_HI    (O_ND + T_ALL*NPTS*DD)             // bf16 hi, frag layout (shorts)
#define O_LO    (O_HI + T_ALL*NPTS*DD/2)
#define O_PV1   (O_LO + T_ALL*NPTS*DD/2)           // per (row, colblock) top1
#define O_PI1   (O_PV1 + T1*NPTS*NPB)
#define O_PV2   (O_PI1 + T1*NPTS*NPB)              // per (row, colblock) top2
#define O_BEST  (O_PV2 + T1*NPTS*NPB)              // u64 [14336]
#define O_WL    (O_BEST + T1*NPTS*2)               // int per-t worklists [7][2048]
#define O_CNT   (O_WL + T1*NPTS)                   // int cntT[8]

typedef __attribute__((ext_vector_type(8))) short short8v;   // 8 bf16 (4 VGPR)
typedef __attribute__((ext_vector_type(4))) float float4v;   // MFMA acc

__device__ __forceinline__ unsigned short f2bf(float x) {    // RNE f32->bf16
    unsigned u = __float_as_uint(x);
    return (unsigned short)((u + 0x7FFFu + ((u >> 16) & 1u)) >> 16);
}
__device__ __forceinline__ float bf2f(unsigned short h) {
    return __uint_as_float(((unsigned)h) << 16);
}
// monotone pack: larger value wins; equal value -> smaller idx wins
__device__ __forceinline__ unsigned long long packVI(float v, int idx) {
    unsigned int b = __float_as_uint(v);
    b = (b & 0x80000000u) ? ~b : (b | 0x80000000u);
    return ((unsigned long long)b << 32) | (unsigned int)(NPTS - 1 - idx);
}

// ---------------------------------------------------------------------------
// Kernel 1: normalize rows; emit fp32 nd + bf16 hi/lo in MFMA-frag layout,
// now staged through LDS so global stores are fully coalesced (R13 wrote
// scattered 8B granules). Block = 16-row frag group (256 thr: row=tid>>4,
// 16-elem chunk kc=tid&15). Global layout byte-identical to R13:
// addr(k) = grp*4096 + (k>>5)*512 + (row&15)*8 + ((k>>2)&3)*128
//           + ((k>>4)&1)*4 + (k&3)   [shorts]
// ---------------------------------------------------------------------------
__global__ __launch_bounds__(256) void prep_kernel(const float* __restrict__ desc,
                                                   float* __restrict__ nd,
                                                   ushort* __restrict__ ghi,
                                                   ushort* __restrict__ glo,
                                                   int* __restrict__ cntT) {
    __shared__ ushort hiS[4096];                   // 8 KB: one 16-row frag group
    __shared__ ushort loS[4096];
    const int tid = threadIdx.x;
    const int grp = blockIdx.x;                    // 0..1023
    if (grp == 0 && tid < 8) cntT[tid] = 0;
    const int rl  = tid >> 4;                      // row in group
    const int kc  = tid & 15;                      // 16-float chunk
    const int row = grp * 16 + rl;

    const float* sp = desc + (size_t)row * DD + kc * 16;
    float4 v[4];
    float s = 0.f;
#pragma unroll
    for (int j = 0; j < 4; ++j) {
        v[j] = reinterpret_cast<const float4*>(sp)[j];
        s += v[j].x * v[j].x + v[j].y * v[j].y + v[j].z * v[j].z + v[j].w * v[j].w;
    }
#pragma unroll
    for (int m = 1; m <= 8; m <<= 1) s += __shfl_xor(s, m, 64);  // 16-lane row group
    float n = fmaxf(sqrtf(s), 1e-8f);

    float4 o[4];
    float* ndp = nd + (size_t)row * DD + kc * 16;
#pragma unroll
    for (int j = 0; j < 4; ++j) {
        o[j] = make_float4(v[j].x / n, v[j].y / n, v[j].z / n, v[j].w / n);
        reinterpret_cast<float4*>(ndp)[j] = o[j];
    }
    const int sbase = (kc >> 1) * 512 + rl * 8 + (kc & 1) * 4;   // shorts
#pragma unroll
    for (int g = 0; g < 4; ++g) {
        float xs[4] = {o[g].x, o[g].y, o[g].z, o[g].w};
        ushort4 h, l;
        h.x = f2bf(xs[0]); l.x = f2bf(xs[0] - bf2f(h.x));
        h.y = f2bf(xs[1]); l.y = f2bf(xs[1] - bf2f(h.y));
        h.z = f2bf(xs[2]); l.z = f2bf(xs[2] - bf2f(h.z));
        h.w = f2bf(xs[3]); l.w = f2bf(xs[3] - bf2f(h.w));
        *reinterpret_cast<ushort4*>(&hiS[sbase + g * 128]) = h;
        *reinterpret_cast<ushort4*>(&loS[sbase + g * 128]) = l;
    }
    __syncthreads();
    // coalesced copy-out: 8 KB each, 32 B/thread
    const uint4* hs = reinterpret_cast<const uint4*>(hiS);
    const uint4* ls = reinterpret_cast<const uint4*>(loS);
    uint4* hd = reinterpret_cast<uint4*>(ghi + (size_t)grp * 4096);
    uint4* ld = reinterpret_cast<uint4*>(glo + (size_t)grp * 4096);
    hd[tid] = hs[tid];  hd[tid + 256] = hs[tid + 256];
    ld[tid] = ls[tid];  ld[tid + 256] = ls[tid + 256];
}

// ---------------------------------------------------------------------------
// Kernel 2: bf16 MFMA match, fused hi/lo + double-buffered DMA + COUNTED
// vmcnt (T4). Per round: issue next round's 8 DMAs, then `s_waitcnt vmcnt(8)`
// (only the PREVIOUS round's 8 must have landed -- they had a full compute
// phase to fly), raw s_barrier, compute, raw s_barrier. R13's __syncthreads
// compiled to a vmcnt(0) drain that waited for the fresh prefetch every
// round (78us vs ~30us LDS/MFMA floor). Never drain vmcnt in the loop.
// ---------------------------------------------------------------------------
__global__ __launch_bounds__(256) void match_kernel(const ushort* __restrict__ ghi,
                                                    const ushort* __restrict__ glo,
                                                    float* __restrict__ pV1,
                                                    int* __restrict__ pI1,
                                                    float* __restrict__ pV2) {
    __shared__ __align__(16) ushort sAB[2][16384];  // 64KB: 2 x (aH|aL|bH|bL)
    const int bid = blockIdx.x;                    // ((t*16)+rb)*16 + cb
    const int cb  = bid & 15;
    const int rb  = (bid >> 4) & 15;
    const int t   = bid >> 8;
    const int tid = threadIdx.x;
    const int w   = tid >> 6;                      // wave 0..3
    const int l   = tid & 63;
    const int wr  = w >> 1;                        // row quadrant
    const int wc  = w & 1;                         // col quadrant

    // DMA staging: wave w owns tensor w (0=a_hi, 1=a_lo, 2=b_hi, 3=b_lo)
    const ushort* tsrc = (w & 1) ? glo : ghi;
    const int rgbase = (w < 2) ? (t * 128 + rb * 8)
                               : ((t + 1) * 128 + cb * 8);

    auto issue = [&](int rd, int buf) {            // 8 x 1KB tile DMAs
#pragma unroll
        for (int i = 0; i < 8; ++i) {
            const ushort* gp = tsrc + (((size_t)(rgbase + i) * 8 + rd) << 9) + (l << 3);
            __builtin_amdgcn_global_load_lds(
                (const __attribute__((address_space(1))) unsigned int*)gp,
                (__attribute__((address_space(3))) unsigned int*)&sAB[buf][(w * 8 + i) << 9],
                16, 0, 0);
        }
    };

    float4v acc[4][4];
#pragma unroll
    for (int fa = 0; fa < 4; ++fa)
#pragma unroll
        for (int fb = 0; fb < 4; ++fb) acc[fa][fb] = (float4v){0.f, 0.f, 0.f, 0.f};

    issue(0, 0);                                   // 8 in flight
#pragma unroll 1
    for (int rd = 0; rd < 8; ++rd) {
        const int cur = rd & 1;
        if (rd < 7) {
            issue(rd + 1, cur ^ 1);                // 16 in flight
            asm volatile("s_waitcnt vmcnt(8)" ::: "memory");   // oldest 8 landed
        } else {
            asm volatile("s_waitcnt vmcnt(0)" ::: "memory");   // last round: all
        }
        __builtin_amdgcn_s_barrier();              // buf[cur] published block-wide
        __builtin_amdgcn_sched_barrier(0);         // pin reads after the wait
        const ushort* S = sAB[cur];
        short8v bh[4], bl[4];
#pragma unroll
        for (int f = 0; f < 4; ++f) {
            bh[f] = *reinterpret_cast<const short8v*>(&S[((16 + wc * 4 + f) << 9) + l * 8]);
            bl[f] = *reinterpret_cast<const short8v*>(&S[((24 + wc * 4 + f) << 9) + l * 8]);
        }
#pragma unroll
        for (int fa = 0; fa < 4; ++fa) {
            short8v ah = *reinterpret_cast<const short8v*>(&S[(((wr * 4 + fa)) << 9) + l * 8]);
            short8v al = *reinterpret_cast<const short8v*>(&S[((8 + wr * 4 + fa) << 9) + l * 8]);
#pragma unroll
            for (int fb = 0; fb < 4; ++fb)
                acc[fa][fb] = __builtin_amdgcn_mfma_f32_16x16x32_bf16(ah, bh[fb], acc[fa][fb], 0, 0, 0);
#pragma unroll
            for (int fb = 0; fb < 4; ++fb)
                acc[fa][fb] = __builtin_amdgcn_mfma_f32_16x16x32_bf16(ah, bl[fb], acc[fa][fb], 0, 0, 0);
#pragma unroll
            for (int fb = 0; fb < 4; ++fb)
                acc[fa][fb] = __builtin_amdgcn_mfma_f32_16x16x32_bf16(al, bh[fb], acc[fa][fb], 0, 0, 0);
        }
        __builtin_amdgcn_s_barrier();              // readers done before overwrite
    }

    // ---- epilogue: D row = wr*64+fa*16+4*(l>>4)+r, col = wc*64+fb*16+(l&15)
    float* exV1 = (float*)sAB;                     // [2][128] (aliases buf0)
    int*   exI1 = (int*)sAB + 256;
    float* exV2 = (float*)sAB + 512;
#pragma unroll
    for (int fa = 0; fa < 4; ++fa) {
#pragma unroll
        for (int r = 0; r < 4; ++r) {
            float v1 = -3.0e38f, v2 = -3.0e38f; int i1 = 0;
#pragma unroll
            for (int fb = 0; fb < 4; ++fb) {
                float x  = acc[fa][fb][r];
                int  col = cb * 128 + wc * 64 + fb * 16 + (l & 15);
                if (x > v1) { v2 = v1; v1 = x; i1 = col; }
                else        { v2 = fmaxf(v2, x); }
            }
#pragma unroll
            for (int m = 1; m <= 8; m <<= 1) {     // 16-lane butterfly
                float ov1 = __shfl_xor(v1, m);
                int   oi1 = __shfl_xor(i1, m);
                float ov2 = __shfl_xor(v2, m);
                bool take = (ov1 > v1) || (ov1 == v1 && oi1 < i1);
                float nv2 = take ? fmaxf(ov2, v1) : fmaxf(v2, ov1);
                v1 = take ? ov1 : v1;  i1 = take ? oi1 : i1;  v2 = nv2;
            }
            if ((l & 15) == 0) {
                int rloc = wr * 64 + fa * 16 + (l >> 4) * 4 + r;
                exV1[wc * 128 + rloc] = v1;
                exI1[wc * 128 + rloc] = i1;
                exV2[wc * 128 + rloc] = v2;
            }
        }
    }
    __syncthreads();
    if (tid < 128) {
        float v1 = exV1[tid];       int i1 = exI1[tid];       float v2 = exV2[tid];
        float b1 = exV1[128 + tid]; int bi = exI1[128 + tid]; float b2 = exV2[128 + tid];
        bool take = (b1 > v1) || (b1 == v1 && bi < i1);
        float nv2 = take ? fmaxf(b2, v1) : fmaxf(v2, b1);
        if (take) { v1 = b1; i1 = bi; }
        int idx = (t * NPTS + rb * 128 + tid) * NPB + cb;
        pV1[idx] = v1; pI1[idx] = i1; pV2[idx] = nv2;
    }
}

// ---------------------------------------------------------------------------
// Kernel 3: global top-2 margin per row; near-ties -> per-t worklist; safe
// rows commit approx best (value error <= 4.8e-5 << bf16-granular bar).
// ---------------------------------------------------------------------------
__global__ __launch_bounds__(256) void margin_kernel(const float* __restrict__ pV1,
                                                     const int* __restrict__ pI1,
                                                     const float* __restrict__ pV2,
                                                     unsigned long long* __restrict__ best,
                                                     int* __restrict__ wlT,
                                                     int* __restrict__ cntT) {
    int r = blockIdx.x * 256 + threadIdx.x;        // 0..14335
    int t = r >> 11;
    float v1 = -3.0e38f, v2 = -3.0e38f; int i1 = 0;
#pragma unroll
    for (int cbk = 0; cbk < NPB; ++cbk) {          // ascending -> first-occurrence
        int idx = r * NPB + cbk;
        float a1 = pV1[idx]; int ai = pI1[idx]; float a2 = pV2[idx];
        if (a1 > v1) { v2 = fmaxf(v1, a2); v1 = a1; i1 = ai; }
        else         { v2 = fmaxf(v2, a1); }
    }
    if (v1 - v2 < MARGIN_THR) {
        best[r] = 0ull;
        int slot = atomicAdd(&cntT[t], 1);
        wlT[t * NPTS + slot] = r & (NPTS - 1);     // row within frame
    } else {
        best[r] = packVI(v1, i1);
    }
}

// ---------------------------------------------------------------------------
// Kernel 4: exact fp32 rescore, loop-inverted + wave-parallel rows.
// Block = (t, 8-col slab); batch-stage <=24 flagged src rows + the dst slab
// in conflict-free [*][8][33] layouts; wave w handles rows w, w+4, ...
// independently; one atomicMax per row per slab (order-independent).
// ---------------------------------------------------------------------------
__global__ __launch_bounds__(256) void recheck_kernel(const float* __restrict__ nd,
                                                      const int* __restrict__ wlT,
                                                      const int* __restrict__ cntT,
                                                      unsigned long long* __restrict__ best) {
    __shared__ float dstS[RC_COLS][8][33];         // 8.25 KB  [col][kseg][k]
    __shared__ float srcS[RC_ROWS][8][33];         // 24.75 KB [row][kseg][k]
    const int t   = blockIdx.x >> 8;               // grid = 7 * 256
    const int cc  = blockIdx.x & 255;
    const int nr  = cntT[t];
    if (nr == 0) return;
    const int tid  = threadIdx.x;
    const int w    = tid >> 6;
    const int l    = tid & 63;
    const int col0 = cc * RC_COLS;

    {   // stage 8 dst cols: thread col=tid>>5, 2 float4 (8 floats) each
        const int col = tid >> 5;
        const int k8  = tid & 31;
        const float* dp = nd + ((size_t)((t + 1) * NPTS) + col0 + col) * DD;
#pragma unroll
        for (int j = 0; j < 2; ++j) {
            float4 v = reinterpret_cast<const float4*>(dp)[k8 * 2 + j];
            int k = (k8 * 2 + j) * 4;
            dstS[col][k >> 5][k & 31]       = v.x;
            dstS[col][(k+1) >> 5][(k+1)&31] = v.y;
            dstS[col][(k+2) >> 5][(k+2)&31] = v.z;
            dstS[col][(k+3) >> 5][(k+3)&31] = v.w;
        }
    }

#pragma unroll 1
    for (int base = 0; base < nr; base += RC_ROWS) {
        const int nb = min(RC_ROWS, nr - base);
        __syncthreads();                           // srcS free (dstS ready, 1st)
        for (int idx = tid; idx < nb * 64; idx += 256) {
            const int ri = idx >> 6, ln = idx & 63;
            const int row = wlT[t * NPTS + base + ri];
            float4 v = reinterpret_cast<const float4*>(
                nd + ((size_t)(t * NPTS) + row) * DD)[ln];
            int k = ln * 4;
            srcS[ri][k >> 5][k & 31]       = v.x;
            srcS[ri][(k+1) >> 5][(k+1)&31] = v.y;
            srcS[ri][(k+2) >> 5][(k+2)&31] = v.z;
            srcS[ri][(k+3) >> 5][(k+3)&31] = v.w;
        }
        __syncthreads();                           // batch staged

        const int colx = l & 7, ks = l >> 3;
#pragma unroll 1
        for (int ri = w; ri < nb; ri += 4) {       // waves independent
            const int row = wlT[t * NPTS + base + ri];
            const int r   = t * NPTS + row;
            float p = 0.f;
#pragma unroll
            for (int k = 0; k < 32; ++k)
                p = fmaf(srcS[ri][ks][k], dstS[colx][ks][k], p);
            p += __shfl_xor(p, 8); p += __shfl_xor(p, 16); p += __shfl_xor(p, 32);
            float bv = p; int bi = col0 + colx;
#pragma unroll
            for (int m = 1; m <= 4; m <<= 1) {     // top-1 across 8 cols
                float ov = __shfl_xor(bv, m);
                int   oi = __shfl_xor(bi, m);
                if (ov > bv || (ov == bv && oi < bi)) { bv = ov; bi = oi; }
            }
            if (l == 0) atomicMax(&best[r], packVI(bv, bi));
        }
    }
}

// ---------------------------------------------------------------------------
// Kernel 5: unpack best[], gather matched points, write outputs.
// ---------------------------------------------------------------------------
__global__ __launch_bounds__(256) void final_kernel(const unsigned long long* __restrict__ best,
                                                    const float* __restrict__ pts,
                                                    float* __restrict__ out) {
    int r = blockIdx.x * 256 + threadIdx.x;
    int t = r >> 11;
    unsigned long long p = best[r];
    int idx = NPTS - 1 - (int)(p & 0xFFFFFFFFull);
    unsigned int b = (unsigned int)(p >> 32);
    b = (b & 0x80000000u) ? (b & 0x7FFFFFFFu) : ~b;
    out[(size_t)T1 * NPTS * 2 + r] = __uint_as_float(b);
    const float* q = pts + ((size_t)((t + 1) * NPTS) + idx) * 2;
    out[(size_t)r * 2 + 0] = q[0];
    out[(size_t)r * 2 + 1] = q[1];
}

// ---------------------------------------------------------------------------
extern "C" void kernel_launch(void* const* d_in, const int* in_sizes, int n_in,
                              void* d_out, int out_size, void* d_ws, size_t ws_size,
                              hipStream_t stream) {
    const float* desc = (const float*)d_in[0];     // [8, 2048, 256] fp32
    const float* pts  = (const float*)d_in[1];     // [8, 2048, 2]   fp32
    float* ws = (float*)d_ws;
    float* nd  = ws + O_ND;
    ushort* ghi = (ushort*)(ws + O_HI);
    ushort* glo = (ushort*)(ws + O_LO);
    float* pV1 = ws + O_PV1;
    int*   pI1 = (int*)(ws + O_PI1);
    float* pV2 = ws + O_PV2;
    unsigned long long* best = (unsigned long long*)(ws + O_BEST);
    int* wlT  = (int*)(ws + O_WL);
    int* cntT = (int*)(ws + O_CNT);

    prep_kernel<<<T_ALL * NPTS / 16, 256, 0, stream>>>(desc, nd, ghi, glo, cntT);
    match_kernel<<<T1 * 16 * 16, 256, 0, stream>>>(ghi, glo, pV1, pI1, pV2);
    margin_kernel<<<(T1 * NPTS) / 256, 256, 0, stream>>>(pV1, pI1, pV2, best, wlT, cntT);
    recheck_kernel<<<T1 * 256, 256, 0, stream>>>(nd, wlT, cntT, best);
    final_kernel<<<(T1 * NPTS) / 256, 256, 0, stream>>>(best, pts, (float*)d_out);
}

// Round 15
// 124.457 us; speedup vs baseline: 1.3700x; 1.0192x over previous
//
#include <hip/hip_runtime.h>

// Problem constants (fixed by setup_inputs: T=8, N=2048, D=256)
#define T_ALL 8
#define T1    7
#define NPTS  2048
#define DD    256
#define NPB   32                     // 64-col blocks per frame (wave tiles)
#define MARGIN_THR 2.0e-4f           // 2x the 9.6e-5 rigorous (C-S) margin bound
#define RC_COLS 8                    // dst cols per recheck block
#define RC_ROWS 24                   // src rows staged per recheck batch

// ws layout (floats)
#define O_ND    0                                  // fp32 normalized [16384][256]
#define O_HI    (O_ND + T_ALL*NPTS*DD)             // bf16 hi, frag layout (shorts)
#define O_LO    (O_HI + T_ALL*NPTS*DD/2)
#define O_PV1   (O_LO + T_ALL*NPTS*DD/2)           // per (row, colblock) top1
#define O_PI1   (O_PV1 + T1*NPTS*NPB)
#define O_PV2   (O_PI1 + T1*NPTS*NPB)              // per (row, colblock) top2
#define O_BEST  (O_PV2 + T1*NPTS*NPB)              // u64 [14336]
#define O_WL    (O_BEST + T1*NPTS*2)               // int per-t worklists [7][2048]
#define O_CNT   (O_WL + T1*NPTS)                   // int cntT[8]

typedef __attribute__((ext_vector_type(8))) short short8v;   // 8 bf16 (4 VGPR)
typedef __attribute__((ext_vector_type(4))) float float4v;   // MFMA acc

__device__ __forceinline__ unsigned short f2bf(float x) {    // RNE f32->bf16
    unsigned u = __float_as_uint(x);
    return (unsigned short)((u + 0x7FFFu + ((u >> 16) & 1u)) >> 16);
}
__device__ __forceinline__ float bf2f(unsigned short h) {
    return __uint_as_float(((unsigned)h) << 16);
}
// monotone pack: larger value wins; equal value -> smaller idx wins
__device__ __forceinline__ unsigned long long packVI(float v, int idx) {
    unsigned int b = __float_as_uint(v);
    b = (b & 0x80000000u) ? ~b : (b | 0x80000000u);
    return ((unsigned long long)b << 32) | (unsigned int)(NPTS - 1 - idx);
}

// ---------------------------------------------------------------------------
// Kernel 1: normalize rows; emit fp32 nd + bf16 hi/lo in MFMA-frag layout,
// staged through LDS so global stores are fully coalesced. Block = 16-row
// frag group. Each (16-row group, 32-k step) is a contiguous 1KB tile whose
// bytes are lane-contiguous (lane*16B) -> waves can load fragments DIRECTLY
// from global. A and B use the SAME (lane,e)->k map, so any HW k-permutation
// cancels in the dot product.
// ---------------------------------------------------------------------------
__global__ __launch_bounds__(256) void prep_kernel(const float* __restrict__ desc,
                                                   float* __restrict__ nd,
                                                   ushort* __restrict__ ghi,
                                                   ushort* __restrict__ glo,
                                                   int* __restrict__ cntT) {
    __shared__ ushort hiS[4096];                   // 8 KB: one 16-row frag group
    __shared__ ushort loS[4096];
    const int tid = threadIdx.x;
    const int grp = blockIdx.x;                    // 0..1023
    if (grp == 0 && tid < 8) cntT[tid] = 0;
    const int rl  = tid >> 4;                      // row in group
    const int kc  = tid & 15;                      // 16-float chunk
    const int row = grp * 16 + rl;

    const float* sp = desc + (size_t)row * DD + kc * 16;
    float4 v[4];
    float s = 0.f;
#pragma unroll
    for (int j = 0; j < 4; ++j) {
        v[j] = reinterpret_cast<const float4*>(sp)[j];
        s += v[j].x * v[j].x + v[j].y * v[j].y + v[j].z * v[j].z + v[j].w * v[j].w;
    }
#pragma unroll
    for (int m = 1; m <= 8; m <<= 1) s += __shfl_xor(s, m, 64);  // 16-lane row group
    float n = fmaxf(sqrtf(s), 1e-8f);

    float4 o[4];
    float* ndp = nd + (size_t)row * DD + kc * 16;
#pragma unroll
    for (int j = 0; j < 4; ++j) {
        o[j] = make_float4(v[j].x / n, v[j].y / n, v[j].z / n, v[j].w / n);
        reinterpret_cast<float4*>(ndp)[j] = o[j];
    }
    const int sbase = (kc >> 1) * 512 + rl * 8 + (kc & 1) * 4;   // shorts
#pragma unroll
    for (int g = 0; g < 4; ++g) {
        float xs[4] = {o[g].x, o[g].y, o[g].z, o[g].w};
        ushort4 h, l;
        h.x = f2bf(xs[0]); l.x = f2bf(xs[0] - bf2f(h.x));
        h.y = f2bf(xs[1]); l.y = f2bf(xs[1] - bf2f(h.y));
        h.z = f2bf(xs[2]); l.z = f2bf(xs[2] - bf2f(h.z));
        h.w = f2bf(xs[3]); l.w = f2bf(xs[3] - bf2f(h.w));
        *reinterpret_cast<ushort4*>(&hiS[sbase + g * 128]) = h;
        *reinterpret_cast<ushort4*>(&loS[sbase + g * 128]) = l;
    }
    __syncthreads();
    // coalesced copy-out: 8 KB each, 32 B/thread
    const uint4* hs = reinterpret_cast<const uint4*>(hiS);
    const uint4* ls = reinterpret_cast<const uint4*>(loS);
    uint4* hd = reinterpret_cast<uint4*>(ghi + (size_t)grp * 4096);
    uint4* ld = reinterpret_cast<uint4*>(glo + (size_t)grp * 4096);
    hd[tid] = hs[tid];  hd[tid + 256] = hs[tid + 256];
    ld[tid] = ls[tid];  ld[tid + 256] = ls[tid + 256];
}

// ---------------------------------------------------------------------------
// Kernel 2: bf16 MFMA match, DIRECT global->register fragments. One wave
// (64 thr) per 64x64 output tile; NO LDS, NO barriers in the whole loop.
// R12-R14's LDS staging capped residency at ~6 waves/CU (64KB LDS, lockstep
// barriers) -> 78us vs the ~22us MFMA / ~27us L2-BW floors. Direct loads
// are perfectly coalesced (frag tiles are lane-contiguous 1KB), ~120 VGPR
// -> ~16 waves/CU of pure TLP, loads interleave with MFMA AITER-style.
// Fused hi/lo: hh+hl+lh into one accumulator, 48 MFMAs / 16 loads / round.
// Bijective chunked XCD swizzle: each XCD works ~one frame (~4MB = its L2).
// ---------------------------------------------------------------------------
__global__ __launch_bounds__(64) void match_kernel(const ushort* __restrict__ ghi,
                                                   const ushort* __restrict__ glo,
                                                   float* __restrict__ pV1,
                                                   int* __restrict__ pI1,
                                                   float* __restrict__ pV2) {
    const int bid = blockIdx.x;                    // 7168 = 7 * 32 * 32
    const int swz = (bid & 7) * (7168 / 8) + (bid >> 3);   // bijective (7168%8==0)
    const int t   = swz >> 10;
    const int rb  = (swz >> 5) & 31;               // 64-row panel
    const int cb  = swz & 31;                      // 64-col panel
    const int l   = threadIdx.x;
    const size_t l8 = (size_t)(l << 3);            // lane's 8 shorts

    const int agrp = t * 128 + rb * 4;             // A frag groups (16 rows each)
    const int bgrp = (t + 1) * 128 + cb * 4;       // B frag groups

    float4v acc[4][4];
#pragma unroll
    for (int fa = 0; fa < 4; ++fa)
#pragma unroll
        for (int fb = 0; fb < 4; ++fb) acc[fa][fb] = (float4v){0.f, 0.f, 0.f, 0.f};

#pragma unroll 1
    for (int rd = 0; rd < 8; ++rd) {
        short8v bh[4], bl[4];
#pragma unroll
        for (int fb = 0; fb < 4; ++fb) {
            const size_t off = (((size_t)(bgrp + fb) * 8 + rd) << 9) + l8;
            bh[fb] = *reinterpret_cast<const short8v*>(ghi + off);
            bl[fb] = *reinterpret_cast<const short8v*>(glo + off);
        }
#pragma unroll
        for (int fa = 0; fa < 4; ++fa) {
            const size_t aoff = (((size_t)(agrp + fa) * 8 + rd) << 9) + l8;
            short8v ah = *reinterpret_cast<const short8v*>(ghi + aoff);
            short8v al = *reinterpret_cast<const short8v*>(glo + aoff);
#pragma unroll
            for (int fb = 0; fb < 4; ++fb)
                acc[fa][fb] = __builtin_amdgcn_mfma_f32_16x16x32_bf16(ah, bh[fb], acc[fa][fb], 0, 0, 0);
#pragma unroll
            for (int fb = 0; fb < 4; ++fb)
                acc[fa][fb] = __builtin_amdgcn_mfma_f32_16x16x32_bf16(ah, bl[fb], acc[fa][fb], 0, 0, 0);
#pragma unroll
            for (int fb = 0; fb < 4; ++fb)
                acc[fa][fb] = __builtin_amdgcn_mfma_f32_16x16x32_bf16(al, bh[fb], acc[fa][fb], 0, 0, 0);
        }
    }

    // ---- epilogue (in-wave): D row = fa*16+4*(l>>4)+r, col = cb*64+fb*16+(l&15)
#pragma unroll
    for (int fa = 0; fa < 4; ++fa) {
#pragma unroll
        for (int r = 0; r < 4; ++r) {
            float v1 = -3.0e38f, v2 = -3.0e38f; int i1 = 0;
#pragma unroll
            for (int fb = 0; fb < 4; ++fb) {
                float x  = acc[fa][fb][r];
                int  col = cb * 64 + fb * 16 + (l & 15);
                if (x > v1) { v2 = v1; v1 = x; i1 = col; }
                else        { v2 = fmaxf(v2, x); }
            }
#pragma unroll
            for (int m = 1; m <= 8; m <<= 1) {     // 16-lane butterfly
                float ov1 = __shfl_xor(v1, m);
                int   oi1 = __shfl_xor(i1, m);
                float ov2 = __shfl_xor(v2, m);
                bool take = (ov1 > v1) || (ov1 == v1 && oi1 < i1);
                float nv2 = take ? fmaxf(ov2, v1) : fmaxf(v2, ov1);
                v1 = take ? ov1 : v1;  i1 = take ? oi1 : i1;  v2 = nv2;
            }
            if ((l & 15) == 0) {
                int grow = t * NPTS + rb * 64 + fa * 16 + (l >> 4) * 4 + r;
                int idx  = grow * NPB + cb;
                pV1[idx] = v1; pI1[idx] = i1; pV2[idx] = v2;
            }
        }
    }
}

// ---------------------------------------------------------------------------
// Kernel 3: global top-2 margin per row; near-ties -> per-t worklist; safe
// rows commit approx best (value error <= 4.8e-5 << bf16-granular bar).
// ---------------------------------------------------------------------------
__global__ __launch_bounds__(256) void margin_kernel(const float* __restrict__ pV1,
                                                     const int* __restrict__ pI1,
                                                     const float* __restrict__ pV2,
                                                     unsigned long long* __restrict__ best,
                                                     int* __restrict__ wlT,
                                                     int* __restrict__ cntT) {
    int r = blockIdx.x * 256 + threadIdx.x;        // 0..14335
    int t = r >> 11;
    float v1 = -3.0e38f, v2 = -3.0e38f; int i1 = 0;
#pragma unroll
    for (int cbk = 0; cbk < NPB; ++cbk) {          // ascending -> first-occurrence
        int idx = r * NPB + cbk;
        float a1 = pV1[idx]; int ai = pI1[idx]; float a2 = pV2[idx];
        if (a1 > v1) { v2 = fmaxf(v1, a2); v1 = a1; i1 = ai; }
        else         { v2 = fmaxf(v2, a1); }
    }
    if (v1 - v2 < MARGIN_THR) {
        best[r] = 0ull;
        int slot = atomicAdd(&cntT[t], 1);
        wlT[t * NPTS + slot] = r & (NPTS - 1);     // row within frame
    } else {
        best[r] = packVI(v1, i1);
    }
}

// ---------------------------------------------------------------------------
// Kernel 4: exact fp32 rescore, loop-inverted + wave-parallel rows.
// Block = (t, 8-col slab); batch-stage <=24 flagged src rows + the dst slab
// in conflict-free [*][8][33] layouts; wave w handles rows w, w+4, ...
// independently; one atomicMax per row per slab (order-independent).
// ---------------------------------------------------------------------------
__global__ __launch_bounds__(256) void recheck_kernel(const float* __restrict__ nd,
                                                      const int* __restrict__ wlT,
                                                      const int* __restrict__ cntT,
                                                      unsigned long long* __restrict__ best) {
    __shared__ float dstS[RC_COLS][8][33];         // 8.25 KB  [col][kseg][k]
    __shared__ float srcS[RC_ROWS][8][33];         // 24.75 KB [row][kseg][k]
    const int t   = blockIdx.x >> 8;               // grid = 7 * 256
    const int cc  = blockIdx.x & 255;
    const int nr  = cntT[t];
    if (nr == 0) return;
    const int tid  = threadIdx.x;
    const int w    = tid >> 6;
    const int l    = tid & 63;
    const int col0 = cc * RC_COLS;

    {   // stage 8 dst cols: thread col=tid>>5, 2 float4 (8 floats) each
        const int col = tid >> 5;
        const int k8  = tid & 31;
        const float* dp = nd + ((size_t)((t + 1) * NPTS) + col0 + col) * DD;
#pragma unroll
        for (int j = 0; j < 2; ++j) {
            float4 v = reinterpret_cast<const float4*>(dp)[k8 * 2 + j];
            int k = (k8 * 2 + j) * 4;
            dstS[col][k >> 5][k & 31]       = v.x;
            dstS[col][(k+1) >> 5][(k+1)&31] = v.y;
            dstS[col][(k+2) >> 5][(k+2)&31] = v.z;
            dstS[col][(k+3) >> 5][(k+3)&31] = v.w;
        }
    }

#pragma unroll 1
    for (int base = 0; base < nr; base += RC_ROWS) {
        const int nb = min(RC_ROWS, nr - base);
        __syncthreads();                           // srcS free (dstS ready, 1st)
        for (int idx = tid; idx < nb * 64; idx += 256) {
            const int ri = idx >> 6, ln = idx & 63;
            const int row = wlT[t * NPTS + base + ri];
            float4 v = reinterpret_cast<const float4*>(
                nd + ((size_t)(t * NPTS) + row) * DD)[ln];
            int k = ln * 4;
            srcS[ri][k >> 5][k & 31]       = v.x;
            srcS[ri][(k+1) >> 5][(k+1)&31] = v.y;
            srcS[ri][(k+2) >> 5][(k+2)&31] = v.z;
            srcS[ri][(k+3) >> 5][(k+3)&31] = v.w;
        }
        __syncthreads();                           // batch staged

        const int colx = l & 7, ks = l >> 3;
#pragma unroll 1
        for (int ri = w; ri < nb; ri += 4) {       // waves independent
            const int row = wlT[t * NPTS + base + ri];
            const int r   = t * NPTS + row;
            float p = 0.f;
#pragma unroll
            for (int k = 0; k < 32; ++k)
                p = fmaf(srcS[ri][ks][k], dstS[colx][ks][k], p);
            p += __shfl_xor(p, 8); p += __shfl_xor(p, 16); p += __shfl_xor(p, 32);
            float bv = p; int bi = col0 + colx;
#pragma unroll
            for (int m = 1; m <= 4; m <<= 1) {     // top-1 across 8 cols
                float ov = __shfl_xor(bv, m);
                int   oi = __shfl_xor(bi, m);
                if (ov > bv || (ov == bv && oi < bi)) { bv = ov; bi = oi; }
            }
            if (l == 0) atomicMax(&best[r], packVI(bv, bi));
        }
    }
}

// ---------------------------------------------------------------------------
// Kernel 5: unpack best[], gather matched points, write outputs.
// ---------------------------------------------------------------------------
__global__ __launch_bounds__(256) void final_kernel(const unsigned long long* __restrict__ best,
                                                    const float* __restrict__ pts,
                                                    float* __restrict__ out) {
    int r = blockIdx.x * 256 + threadIdx.x;
    int t = r >> 11;
    unsigned long long p = best[r];
    int idx = NPTS - 1 - (int)(p & 0xFFFFFFFFull);
    unsigned int b = (unsigned int)(p >> 32);
    b = (b & 0x80000000u) ? (b & 0x7FFFFFFFu) : ~b;
    out[(size_t)T1 * NPTS * 2 + r] = __uint_as_float(b);
    const float* q = pts + ((size_t)((t + 1) * NPTS) + idx) * 2;
    out[(size_t)r * 2 + 0] = q[0];
    out[(size_t)r * 2 + 1] = q[1];
}

// ---------------------------------------------------------------------------
extern "C" void kernel_launch(void* const* d_in, const int* in_sizes, int n_in,
                              void* d_out, int out_size, void* d_ws, size_t ws_size,
                              hipStream_t stream) {
    const float* desc = (const float*)d_in[0];     // [8, 2048, 256] fp32
    const float* pts  = (const float*)d_in[1];     // [8, 2048, 2]   fp32
    float* ws = (float*)d_ws;
    float* nd  = ws + O_ND;
    ushort* ghi = (ushort*)(ws + O_HI);
    ushort* glo = (ushort*)(ws + O_LO);
    float* pV1 = ws + O_PV1;
    int*   pI1 = (int*)(ws + O_PI1);
    float* pV2 = ws + O_PV2;
    unsigned long long* best = (unsigned long long*)(ws + O_BEST);
    int* wlT  = (int*)(ws + O_WL);
    int* cntT = (int*)(ws + O_CNT);

    prep_kernel<<<T_ALL * NPTS / 16, 256, 0, stream>>>(desc, nd, ghi, glo, cntT);
    match_kernel<<<T1 * 32 * 32, 64, 0, stream>>>(ghi, glo, pV1, pI1, pV2);
    margin_kernel<<<(T1 * NPTS) / 256, 256, 0, stream>>>(pV1, pI1, pV2, best, wlT, cntT);
    recheck_kernel<<<T1 * 256, 256, 0, stream>>>(nd, wlT, cntT, best);
    final_kernel<<<(T1 * NPTS) / 256, 256, 0, stream>>>(best, pts, (float*)d_out);
}

// Round 16
// 121.858 us; speedup vs baseline: 1.3992x; 1.0213x over previous
//
#include <hip/hip_runtime.h>

// Problem constants (fixed by setup_inputs: T=8, N=2048, D=256)
#define T_ALL 8
#define T1    7
#define NPTS  2048
#define DD    256
#define NPB   32                     // 64-col blocks per frame (wave tiles)
#define MARGIN_THR 2.0e-4f           // 2x the 9.6e-5 rigorous (C-S) margin bound
#define RC_COLS 8                    // dst cols per recheck block
#define RC_ROWS 24                   // src rows staged per recheck batch

// ws layout (floats)
#define O_ND    0                                  // fp32 normalized [16384][256]
#define O_HI    (O_ND + T_ALL*NPTS*DD)             // bf16 hi, frag layout (shorts)
#define O_LO    (O_HI + T_ALL*NPTS*DD/2)
#define O_PV1   (O_LO + T_ALL*NPTS*DD/2)           // per (row, colblock) top1
#define O_PI1   (O_PV1 + T1*NPTS*NPB)
#define O_PV2   (O_PI1 + T1*NPTS*NPB)              // per (row, colblock) top2
#define O_BEST  (O_PV2 + T1*NPTS*NPB)              // u64 [14336]
#define O_WL    (O_BEST + T1*NPTS*2)               // int per-t worklists [7][2048]
#define O_CNT   (O_WL + T1*NPTS)                   // int cntT[8]

typedef __attribute__((ext_vector_type(8))) short short8v;   // 8 bf16 (4 VGPR)
typedef __attribute__((ext_vector_type(4))) float float4v;   // MFMA acc

__device__ __forceinline__ unsigned short f2bf(float x) {    // RNE f32->bf16
    unsigned u = __float_as_uint(x);
    return (unsigned short)((u + 0x7FFFu + ((u >> 16) & 1u)) >> 16);
}
__device__ __forceinline__ float bf2f(unsigned short h) {
    return __uint_as_float(((unsigned)h) << 16);
}
// monotone pack: larger value wins; equal value -> smaller idx wins
__device__ __forceinline__ unsigned long long packVI(float v, int idx) {
    unsigned int b = __float_as_uint(v);
    b = (b & 0x80000000u) ? ~b : (b | 0x80000000u);
    return ((unsigned long long)b << 32) | (unsigned int)(NPTS - 1 - idx);
}

// ---------------------------------------------------------------------------
// Kernel 1: normalize rows; emit fp32 nd + bf16 hi/lo in MFMA-frag layout,
// staged through LDS so global stores are fully coalesced. Block = 16-row
// frag group. Each (16-row group, 32-k step) is a contiguous 1KB tile whose
// bytes are lane-contiguous (lane*16B) -> waves load fragments DIRECTLY
// from global. A and B use the SAME (lane,e)->k map, so any HW k-permutation
// cancels in the dot product.
// ---------------------------------------------------------------------------
__global__ __launch_bounds__(256) void prep_kernel(const float* __restrict__ desc,
                                                   float* __restrict__ nd,
                                                   ushort* __restrict__ ghi,
                                                   ushort* __restrict__ glo,
                                                   int* __restrict__ cntT) {
    __shared__ ushort hiS[4096];                   // 8 KB: one 16-row frag group
    __shared__ ushort loS[4096];
    const int tid = threadIdx.x;
    const int grp = blockIdx.x;                    // 0..1023
    if (grp == 0 && tid < 8) cntT[tid] = 0;
    const int rl  = tid >> 4;                      // row in group
    const int kc  = tid & 15;                      // 16-float chunk
    const int row = grp * 16 + rl;

    const float* sp = desc + (size_t)row * DD + kc * 16;
    float4 v[4];
    float s = 0.f;
#pragma unroll
    for (int j = 0; j < 4; ++j) {
        v[j] = reinterpret_cast<const float4*>(sp)[j];
        s += v[j].x * v[j].x + v[j].y * v[j].y + v[j].z * v[j].z + v[j].w * v[j].w;
    }
#pragma unroll
    for (int m = 1; m <= 8; m <<= 1) s += __shfl_xor(s, m, 64);  // 16-lane row group
    float n = fmaxf(sqrtf(s), 1e-8f);

    float4 o[4];
    float* ndp = nd + (size_t)row * DD + kc * 16;
#pragma unroll
    for (int j = 0; j < 4; ++j) {
        o[j] = make_float4(v[j].x / n, v[j].y / n, v[j].z / n, v[j].w / n);
        reinterpret_cast<float4*>(ndp)[j] = o[j];
    }
    const int sbase = (kc >> 1) * 512 + rl * 8 + (kc & 1) * 4;   // shorts
#pragma unroll
    for (int g = 0; g < 4; ++g) {
        float xs[4] = {o[g].x, o[g].y, o[g].z, o[g].w};
        ushort4 h, l;
        h.x = f2bf(xs[0]); l.x = f2bf(xs[0] - bf2f(h.x));
        h.y = f2bf(xs[1]); l.y = f2bf(xs[1] - bf2f(h.y));
        h.z = f2bf(xs[2]); l.z = f2bf(xs[2] - bf2f(h.z));
        h.w = f2bf(xs[3]); l.w = f2bf(xs[3] - bf2f(h.w));
        *reinterpret_cast<ushort4*>(&hiS[sbase + g * 128]) = h;
        *reinterpret_cast<ushort4*>(&loS[sbase + g * 128]) = l;
    }
    __syncthreads();
    // coalesced copy-out: 8 KB each, 32 B/thread
    const uint4* hs = reinterpret_cast<const uint4*>(hiS);
    const uint4* ls = reinterpret_cast<const uint4*>(loS);
    uint4* hd = reinterpret_cast<uint4*>(ghi + (size_t)grp * 4096);
    uint4* ld = reinterpret_cast<uint4*>(glo + (size_t)grp * 4096);
    hd[tid] = hs[tid];  hd[tid + 256] = hs[tid + 256];
    ld[tid] = ls[tid];  ld[tid + 256] = ls[tid + 256];
}

// ---------------------------------------------------------------------------
// Kernel 2: bf16 MFMA match, direct global->register fragments with
// REGISTER DOUBLE-BUFFERING. One wave per 64x64 tile, no LDS, no barriers.
// R15 exposed full L2 latency every round (load -> vmcnt wait -> MFMA with
// zero prefetch distance: MfmaUtil 23%). Two named fragment sets E/O,
// loop unrolled x2: load(rd+1 -> O); compute(E); load(rd+2 -> E); compute(O).
// Each set's 16 loads get a ~230-cyc MFMA window to fly -> L2 latency
// (~200cyc) covered purely by dataflow. All frag indexing static (rule #20).
// Fused hi/lo: hh+hl+lh into one accumulator, 48 MFMAs / 16 loads / round.
// Bijective chunked XCD swizzle: each XCD works ~one frame (~its L2).
// ---------------------------------------------------------------------------
__global__ __launch_bounds__(64) void match_kernel(const ushort* __restrict__ ghi,
                                                   const ushort* __restrict__ glo,
                                                   float* __restrict__ pV1,
                                                   int* __restrict__ pI1,
                                                   float* __restrict__ pV2) {
    const int bid = blockIdx.x;                    // 7168 = 7 * 32 * 32
    const int swz = (bid & 7) * (7168 / 8) + (bid >> 3);   // bijective (7168%8==0)
    const int t   = swz >> 10;
    const int rb  = (swz >> 5) & 31;               // 64-row panel
    const int cb  = swz & 31;                      // 64-col panel
    const int l   = threadIdx.x;
    const size_t l8 = (size_t)(l << 3);            // lane's 8 shorts

    const int agrp = t * 128 + rb * 4;             // A frag groups (16 rows each)
    const int bgrp = (t + 1) * 128 + cb * 4;       // B frag groups

    float4v acc[4][4];
#pragma unroll
    for (int fa = 0; fa < 4; ++fa)
#pragma unroll
        for (int fb = 0; fb < 4; ++fb) acc[fa][fb] = (float4v){0.f, 0.f, 0.f, 0.f};

    short8v ahE[4], alE[4], bhE[4], blE[4];        // even-round fragment set
    short8v ahO[4], alO[4], bhO[4], blO[4];        // odd-round fragment set

    auto load = [&](int rd, short8v* ah, short8v* al, short8v* bh, short8v* bl) {
#pragma unroll
        for (int f = 0; f < 4; ++f) {
            const size_t aoff = (((size_t)(agrp + f) * 8 + rd) << 9) + l8;
            const size_t boff = (((size_t)(bgrp + f) * 8 + rd) << 9) + l8;
            ah[f] = *reinterpret_cast<const short8v*>(ghi + aoff);
            al[f] = *reinterpret_cast<const short8v*>(glo + aoff);
            bh[f] = *reinterpret_cast<const short8v*>(ghi + boff);
            bl[f] = *reinterpret_cast<const short8v*>(glo + boff);
        }
    };
    auto compute = [&](const short8v* ah, const short8v* al,
                       const short8v* bh, const short8v* bl) {
#pragma unroll
        for (int fa = 0; fa < 4; ++fa) {
#pragma unroll
            for (int fb = 0; fb < 4; ++fb)
                acc[fa][fb] = __builtin_amdgcn_mfma_f32_16x16x32_bf16(ah[fa], bh[fb], acc[fa][fb], 0, 0, 0);
#pragma unroll
            for (int fb = 0; fb < 4; ++fb)
                acc[fa][fb] = __builtin_amdgcn_mfma_f32_16x16x32_bf16(ah[fa], bl[fb], acc[fa][fb], 0, 0, 0);
#pragma unroll
            for (int fb = 0; fb < 4; ++fb)
                acc[fa][fb] = __builtin_amdgcn_mfma_f32_16x16x32_bf16(al[fa], bh[fb], acc[fa][fb], 0, 0, 0);
        }
    };

    load(0, ahE, alE, bhE, blE);
#pragma unroll 1
    for (int rd = 0; rd < 8; rd += 2) {
        load(rd + 1, ahO, alO, bhO, blO);          // O-loads fly under E-compute
        compute(ahE, alE, bhE, blE);
        if (rd + 2 < 8) load(rd + 2, ahE, alE, bhE, blE);  // E-loads under O-compute
        compute(ahO, alO, bhO, blO);
    }

    // ---- epilogue (in-wave): D row = fa*16+4*(l>>4)+r, col = cb*64+fb*16+(l&15)
#pragma unroll
    for (int fa = 0; fa < 4; ++fa) {
#pragma unroll
        for (int r = 0; r < 4; ++r) {
            float v1 = -3.0e38f, v2 = -3.0e38f; int i1 = 0;
#pragma unroll
            for (int fb = 0; fb < 4; ++fb) {
                float x  = acc[fa][fb][r];
                int  col = cb * 64 + fb * 16 + (l & 15);
                if (x > v1) { v2 = v1; v1 = x; i1 = col; }
                else        { v2 = fmaxf(v2, x); }
            }
#pragma unroll
            for (int m = 1; m <= 8; m <<= 1) {     // 16-lane butterfly
                float ov1 = __shfl_xor(v1, m);
                int   oi1 = __shfl_xor(i1, m);
                float ov2 = __shfl_xor(v2, m);
                bool take = (ov1 > v1) || (ov1 == v1 && oi1 < i1);
                float nv2 = take ? fmaxf(ov2, v1) : fmaxf(v2, ov1);
                v1 = take ? ov1 : v1;  i1 = take ? oi1 : i1;  v2 = nv2;
            }
            if ((l & 15) == 0) {
                int grow = t * NPTS + rb * 64 + fa * 16 + (l >> 4) * 4 + r;
                int idx  = grow * NPB + cb;
                pV1[idx] = v1; pI1[idx] = i1; pV2[idx] = v2;
            }
        }
    }
}

// ---------------------------------------------------------------------------
// Kernel 3: global top-2 margin per row; near-ties -> per-t worklist; safe
// rows commit approx best (value error <= 4.8e-5 << bf16-granular bar).
// ---------------------------------------------------------------------------
__global__ __launch_bounds__(256) void margin_kernel(const float* __restrict__ pV1,
                                                     const int* __restrict__ pI1,
                                                     const float* __restrict__ pV2,
                                                     unsigned long long* __restrict__ best,
                                                     int* __restrict__ wlT,
                                                     int* __restrict__ cntT) {
    int r = blockIdx.x * 256 + threadIdx.x;        // 0..14335
    int t = r >> 11;
    float v1 = -3.0e38f, v2 = -3.0e38f; int i1 = 0;
#pragma unroll
    for (int cbk = 0; cbk < NPB; ++cbk) {          // ascending -> first-occurrence
        int idx = r * NPB + cbk;
        float a1 = pV1[idx]; int ai = pI1[idx]; float a2 = pV2[idx];
        if (a1 > v1) { v2 = fmaxf(v1, a2); v1 = a1; i1 = ai; }
        else         { v2 = fmaxf(v2, a1); }
    }
    if (v1 - v2 < MARGIN_THR) {
        best[r] = 0ull;
        int slot = atomicAdd(&cntT[t], 1);
        wlT[t * NPTS + slot] = r & (NPTS - 1);     // row within frame
    } else {
        best[r] = packVI(v1, i1);
    }
}

// ---------------------------------------------------------------------------
// Kernel 4: exact fp32 rescore, loop-inverted + wave-parallel rows.
// Block = (t, 8-col slab); batch-stage <=24 flagged src rows + the dst slab
// in conflict-free [*][8][33] layouts; wave w handles rows w, w+4, ...
// independently; one atomicMax per row per slab (order-independent).
// ---------------------------------------------------------------------------
__global__ __launch_bounds__(256) void recheck_kernel(const float* __restrict__ nd,
                                                      const int* __restrict__ wlT,
                                                      const int* __restrict__ cntT,
                                                      unsigned long long* __restrict__ best) {
    __shared__ float dstS[RC_COLS][8][33];         // 8.25 KB  [col][kseg][k]
    __shared__ float srcS[RC_ROWS][8][33];         // 24.75 KB [row][kseg][k]
    const int t   = blockIdx.x >> 8;               // grid = 7 * 256
    const int cc  = blockIdx.x & 255;
    const int nr  = cntT[t];
    if (nr == 0) return;
    const int tid  = threadIdx.x;
    const int w    = tid >> 6;
    const int l    = tid & 63;
    const int col0 = cc * RC_COLS;

    {   // stage 8 dst cols: thread col=tid>>5, 2 float4 (8 floats) each
        const int col = tid >> 5;
        const int k8  = tid & 31;
        const float* dp = nd + ((size_t)((t + 1) * NPTS) + col0 + col) * DD;
#pragma unroll
        for (int j = 0; j < 2; ++j) {
            float4 v = reinterpret_cast<const float4*>(dp)[k8 * 2 + j];
            int k = (k8 * 2 + j) * 4;
            dstS[col][k >> 5][k & 31]       = v.x;
            dstS[col][(k+1) >> 5][(k+1)&31] = v.y;
            dstS[col][(k+2) >> 5][(k+2)&31] = v.z;
            dstS[col][(k+3) >> 5][(k+3)&31] = v.w;
        }
    }

#pragma unroll 1
    for (int base = 0; base < nr; base += RC_ROWS) {
        const int nb = min(RC_ROWS, nr - base);
        __syncthreads();                           // srcS free (dstS ready, 1st)
        for (int idx = tid; idx < nb * 64; idx += 256) {
            const int ri = idx >> 6, ln = idx & 63;
            const int row = wlT[t * NPTS + base + ri];
            float4 v = reinterpret_cast<const float4*>(
                nd + ((size_t)(t * NPTS) + row) * DD)[ln];
            int k = ln * 4;
            srcS[ri][k >> 5][k & 31]       = v.x;
            srcS[ri][(k+1) >> 5][(k+1)&31] = v.y;
            srcS[ri][(k+2) >> 5][(k+2)&31] = v.z;
            srcS[ri][(k+3) >> 5][(k+3)&31] = v.w;
        }
        __syncthreads();                           // batch staged

        const int colx = l & 7, ks = l >> 3;
#pragma unroll 1
        for (int ri = w; ri < nb; ri += 4) {       // waves independent
            const int row = wlT[t * NPTS + base + ri];
            const int r   = t * NPTS + row;
            float p = 0.f;
#pragma unroll
            for (int k = 0; k < 32; ++k)
                p = fmaf(srcS[ri][ks][k], dstS[colx][ks][k], p);
            p += __shfl_xor(p, 8); p += __shfl_xor(p, 16); p += __shfl_xor(p, 32);
            float bv = p; int bi = col0 + colx;
#pragma unroll
            for (int m = 1; m <= 4; m <<= 1) {     // top-1 across 8 cols
                float ov = __shfl_xor(bv, m);
                int   oi = __shfl_xor(bi, m);
                if (ov > bv || (ov == bv && oi < bi)) { bv = ov; bi = oi; }
            }
            if (l == 0) atomicMax(&best[r], packVI(bv, bi));
        }
    }
}

// ---------------------------------------------------------------------------
// Kernel 5: unpack best[], gather matched points, write outputs.
// ---------------------------------------------------------------------------
__global__ __launch_bounds__(256) void final_kernel(const unsigned long long* __restrict__ best,
                                                    const float* __restrict__ pts,
                                                    float* __restrict__ out) {
    int r = blockIdx.x * 256 + threadIdx.x;
    int t = r >> 11;
    unsigned long long p = best[r];
    int idx = NPTS - 1 - (int)(p & 0xFFFFFFFFull);
    unsigned int b = (unsigned int)(p >> 32);
    b = (b & 0x80000000u) ? (b & 0x7FFFFFFFu) : ~b;
    out[(size_t)T1 * NPTS * 2 + r] = __uint_as_float(b);
    const float* q = pts + ((size_t)((t + 1) * NPTS) + idx) * 2;
    out[(size_t)r * 2 + 0] = q[0];
    out[(size_t)r * 2 + 1] = q[1];
}

// ---------------------------------------------------------------------------
extern "C" void kernel_launch(void* const* d_in, const int* in_sizes, int n_in,
                              void* d_out, int out_size, void* d_ws, size_t ws_size,
                              hipStream_t stream) {
    const float* desc = (const float*)d_in[0];     // [8, 2048, 256] fp32
    const float* pts  = (const float*)d_in[1];     // [8, 2048, 2]   fp32
    float* ws = (float*)d_ws;
    float* nd  = ws + O_ND;
    ushort* ghi = (ushort*)(ws + O_HI);
    ushort* glo = (ushort*)(ws + O_LO);
    float* pV1 = ws + O_PV1;
    int*   pI1 = (int*)(ws + O_PI1);
    float* pV2 = ws + O_PV2;
    unsigned long long* best = (unsigned long long*)(ws + O_BEST);
    int* wlT  = (int*)(ws + O_WL);
    int* cntT = (int*)(ws + O_CNT);

    prep_kernel<<<T_ALL * NPTS / 16, 256, 0, stream>>>(desc, nd, ghi, glo, cntT);
    match_kernel<<<T1 * 32 * 32, 64, 0, stream>>>(ghi, glo, pV1, pI1, pV2);
    margin_kernel<<<(T1 * NPTS) / 256, 256, 0, stream>>>(pV1, pI1, pV2, best, wlT, cntT);
    recheck_kernel<<<T1 * 256, 256, 0, stream>>>(nd, wlT, cntT, best);
    final_kernel<<<(T1 * NPTS) / 256, 256, 0, stream>>>(best, pts, (float*)d_out);
}